// Round 1
// baseline (3122.919 us; speedup 1.0000x reference)
//
#include <hip/hip_runtime.h>
#include <cstdint>

#define DEV __device__ __forceinline__

typedef __attribute__((ext_vector_type(8))) short bf16x8;
typedef __attribute__((ext_vector_type(4))) float f32x4;

DEV float bf2f(unsigned short u) { return __uint_as_float(((unsigned)u) << 16); }
DEV unsigned short f2bf(float f) {
  unsigned u = __float_as_uint(f);
  u += 0x7FFFu + ((u >> 16) & 1u);
  return (unsigned short)(u >> 16);
}

DEV void gload_lds16(const void* g, void* lds) {
  __builtin_amdgcn_global_load_lds(
      (const __attribute__((address_space(1))) unsigned int*)g,
      (__attribute__((address_space(3))) unsigned int*)lds, 16, 0, 0);
}

// ---------------- embedding: x = tok_emb[tok] + pos_emb ----------------
__global__ __launch_bounds__(256) void k_embed(const int* __restrict__ tokens,
    const float* __restrict__ tok_emb, const float* __restrict__ pos_emb,
    float* __restrict__ x) {
  int n = blockIdx.x;
  int tok = tokens[n];
  int c = threadIdx.x * 4;
  float4 a = *(const float4*)(tok_emb + (long)tok * 1024 + c);
  float4 p = *(const float4*)(pos_emb + (long)n * 1024 + c);
  float4 r;
  r.x = a.x + p.x; r.y = a.y + p.y; r.z = a.z + p.z; r.w = a.w + p.w;
  *(float4*)(x + (long)n * 1024 + c) = r;
}

// ---------------- layernorm (fp32 in) -> bf16 out ----------------
__global__ __launch_bounds__(256) void k_ln(const float* __restrict__ x,
    const float* __restrict__ g, const float* __restrict__ b,
    unsigned short* __restrict__ out) {
  __shared__ float red[8];
  int row = blockIdx.x, t = threadIdx.x;
  const float* xr = x + (long)row * 1024;
  float4 v = *(const float4*)(xr + t * 4);
  float s = v.x + v.y + v.z + v.w;
#pragma unroll
  for (int off = 32; off; off >>= 1) s += __shfl_xor(s, off);
  if ((t & 63) == 0) red[t >> 6] = s;
  __syncthreads();
  float mean = (red[0] + red[1] + red[2] + red[3]) * (1.0f / 1024.0f);
  float dx = v.x - mean, dy = v.y - mean, dz = v.z - mean, dw = v.w - mean;
  float sq = dx * dx + dy * dy + dz * dz + dw * dw;
#pragma unroll
  for (int off = 32; off; off >>= 1) sq += __shfl_xor(sq, off);
  if ((t & 63) == 0) red[4 + (t >> 6)] = sq;
  __syncthreads();
  float var = (red[4] + red[5] + red[6] + red[7]) * (1.0f / 1024.0f);
  float inv = rsqrtf(var + 1e-5f);
  int c = t * 4;
  float4 gv = *(const float4*)(g + c);
  float4 bv = *(const float4*)(b + c);
  ushort4 o;
  o.x = f2bf(dx * inv * gv.x + bv.x);
  o.y = f2bf(dy * inv * gv.y + bv.y);
  o.z = f2bf(dz * inv * gv.z + bv.z);
  o.w = f2bf(dw * inv * gv.w + bv.w);
  *(ushort4*)(out + (long)row * 1024 + c) = o;
}

// ---------------- weight fp32 (K,N) -> bf16 W^T (Np,Kp), zero-padded ----------------
__global__ __launch_bounds__(256) void k_wconv(const float* __restrict__ src,
    unsigned short* __restrict__ dst, int K, int N, int Kp, int Np,
    long sstride, long dstride) {
  __shared__ float tile[32][33];
  const float* s = src + (long)blockIdx.z * sstride;
  unsigned short* d = dst + (long)blockIdx.z * dstride;
  int n0 = blockIdx.x * 32, k0 = blockIdx.y * 32;
  int t = threadIdx.x;
  int r = t >> 3, c4 = (t & 7) * 4;
  int k = k0 + r;
#pragma unroll
  for (int e = 0; e < 4; ++e) {
    int n = n0 + c4 + e;
    tile[r][c4 + e] = (k < K && n < N) ? s[(long)k * N + n] : 0.0f;
  }
  __syncthreads();
  int nrow = n0 + r;
  ushort4 o;
  o.x = f2bf(tile[c4 + 0][r]);
  o.y = f2bf(tile[c4 + 1][r]);
  o.z = f2bf(tile[c4 + 2][r]);
  o.w = f2bf(tile[c4 + 3][r]);
  (void)Np;
  *(ushort4*)(d + (long)nrow * Kp + k0 + c4) = o;
}

// ---------------- dynamic position bias table: table[rel(0..1023)][head(0..15)] ----------------
__global__ __launch_bounds__(256) void k_dpb(const float* __restrict__ w1,
    const float* __restrict__ b1, const float* __restrict__ w2,
    const float* __restrict__ b2, const float* __restrict__ w3,
    const float* __restrict__ b3, float* __restrict__ table) {
  __shared__ float h1[512], h2[512];
  int r = blockIdx.x, t = threadIdx.x;
  float rf = (float)r;
  for (int c = t; c < 512; c += 256) {
    float v = rf * w1[c] + b1[c];
    h1[c] = v / (1.0f + __expf(-v));  // silu
  }
  __syncthreads();
  for (int c = t; c < 512; c += 256) {
    float acc = b2[c];
    for (int k2 = 0; k2 < 512; ++k2) acc = fmaf(h1[k2], w2[(long)k2 * 512 + c], acc);
    h2[c] = acc / (1.0f + __expf(-acc));
  }
  __syncthreads();
  if (t < 16) {
    float acc = b3[t];
    for (int k2 = 0; k2 < 512; ++k2) acc = fmaf(h2[k2], w3[k2 * 16 + t], acc);
    table[r * 16 + t] = acc;
  }
}

// ---------------- GLU: u = a * gelu_exact(gate), zero-padded to 2752 ----------------
__global__ __launch_bounds__(256) void k_glu(const unsigned short* __restrict__ ff,
    unsigned short* __restrict__ u) {
  int row = blockIdx.x, t = threadIdx.x;
  const unsigned short* fr = ff + (long)row * 5504;
  unsigned short* ur = u + (long)row * 2752;
  for (int c = t; c < 2752; c += 256) {
    float val = 0.0f;
    if (c < 2730) {
      float a = bf2f(fr[c]);
      float gt = bf2f(fr[2730 + c]);
      val = a * (0.5f * gt * (1.0f + erff(gt * 0.70710678118654752f)));
    }
    ur[c] = f2bf(val);
  }
}

// ---------------- local attention (VALU, correctness-first) ----------------
// grid: (64 q-chunks of 8, 16 heads, 4 windows); qkv layout (n, [q|k|v] each 1024) bf16
__global__ __launch_bounds__(256, 2) void k_attn(const unsigned short* __restrict__ qkv,
    const float* __restrict__ table, unsigned short* __restrict__ o) {
  __shared__ float sim[8][1024];
  int qc = blockIdx.x, h = blockIdx.y, wi = blockIdx.z;
  int t = threadIdx.x;
  int q = t >> 5;       // 0..7
  int iw = qc * 8 + q;  // query pos within window, 0..511
  // Q row (scaled by d^-0.5) into registers
  float qreg[64];
  {
    const unsigned short* qrow = qkv + ((long)wi * 512 + iw) * 3072 + h * 64;
#pragma unroll
    for (int c = 0; c < 16; ++c) {
      ushort4 u4 = *(const ushort4*)(qrow + c * 4);
      qreg[c * 4 + 0] = 0.125f * bf2f(u4.x);
      qreg[c * 4 + 1] = 0.125f * bf2f(u4.y);
      qreg[c * 4 + 2] = 0.125f * bf2f(u4.z);
      qreg[c * 4 + 3] = 0.125f * bf2f(u4.w);
    }
  }
  // phase 1: scores. key j in [0,1024): global key pos kg = (wi-1)*512 + j.
  // allowed: j >= iw && j <= iw+512 && (wi>0 || j>=512)
  for (int jj = 0; jj < 32; ++jj) {
    int j = (t & 31) + jj * 32;
    float val = -3.402823466e38f;
    bool allowed = (j >= iw) && (j <= iw + 512) && (wi > 0 || j >= 512);
    if (allowed) {
      const unsigned short* krow =
          qkv + ((long)(wi - 1) * 512 + j) * 3072 + 1024 + h * 64;
      float acc = 0.0f;
#pragma unroll
      for (int c = 0; c < 16; ++c) {
        ushort4 u4 = *(const ushort4*)(krow + c * 4);
        acc = fmaf(qreg[c * 4 + 0], bf2f(u4.x), acc);
        acc = fmaf(qreg[c * 4 + 1], bf2f(u4.y), acc);
        acc = fmaf(qreg[c * 4 + 2], bf2f(u4.z), acc);
        acc = fmaf(qreg[c * 4 + 3], bf2f(u4.w), acc);
      }
      int di = 512 + iw - j;
      if (di < 0) di = -di;
      val = acc + table[di * 16 + h];
    }
    sim[q][j] = val;
  }
  __syncthreads();
  // phase 2: softmax per row, normalized in place
  {
    int w = t >> 6, l = t & 63;
#pragma unroll
    for (int rr = 0; rr < 2; ++rr) {
      int q2 = w * 2 + rr;
      float m = -3.402823466e38f;
#pragma unroll
      for (int c = 0; c < 16; ++c) m = fmaxf(m, sim[q2][l + c * 64]);
#pragma unroll
      for (int off = 32; off; off >>= 1) m = fmaxf(m, __shfl_xor(m, off));
      float p[16];
      float ssum = 0.0f;
#pragma unroll
      for (int c = 0; c < 16; ++c) {
        p[c] = __expf(sim[q2][l + c * 64] - m);
        ssum += p[c];
      }
#pragma unroll
      for (int off = 32; off; off >>= 1) ssum += __shfl_xor(ssum, off);
      float inv = 1.0f / ssum;
#pragma unroll
      for (int c = 0; c < 16; ++c) sim[q2][l + c * 64] = p[c] * inv;
    }
  }
  __syncthreads();
  // phase 3: PV
  {
    int d0 = (t & 31) * 2;
    float o0 = 0.0f, o1 = 0.0f;
    int jstart = (wi == 0) ? 512 : 0;  // padded keys have p == 0; skip OOB memory
    const unsigned short* vbase = qkv + 2048 + h * 64 + d0;
    for (int j = jstart; j < 1024; ++j) {
      float pw = sim[q][j];
      ushort2 u2 = *(const ushort2*)(vbase + ((long)(wi - 1) * 512 + j) * 3072);
      o0 = fmaf(pw, bf2f(u2.x), o0);
      o1 = fmaf(pw, bf2f(u2.y), o1);
    }
    unsigned short* orow = o + ((long)wi * 512 + iw) * 1024 + h * 64 + d0;
    ushort2 st;
    st.x = f2bf(o0);
    st.y = f2bf(o1);
    *(ushort2*)orow = st;
  }
}

// ---------------- GEMM: C(M,N) = A(M,K) * B^T(N,K), bf16 MFMA ----------------
// EPI: 0 = store bf16, 1 = fp32 +=, 2 = store fp32
template <int EPI>
__global__ __launch_bounds__(256, 2) void k_gemm(const unsigned short* __restrict__ A,
    const unsigned short* __restrict__ BT, void* __restrict__ Cout,
    int M, int N, int K) {
  __shared__ unsigned short As[128 * 64];
  __shared__ unsigned short Bs[128 * 64];
  const int bn = blockIdx.x, bm = blockIdx.y;
  const int t = threadIdx.x;
  const int w = t >> 6, l = t & 63;
  const int wm = w >> 1, wn = w & 1;   // 2x2 waves, 64x64 each
  const int lrow = l >> 3, lch = l & 7;
  const int lq = l & 15, lk = l >> 4;
  f32x4 acc[4][4] = {};
  const long arow0 = (long)bm * 128, brow0 = (long)bn * 128;
  for (int kt = 0; kt < K; kt += 64) {
    __syncthreads();
    // stage A,B tiles (128 rows x 64 bf16); XOR-swizzle pre-applied on the GLOBAL
    // source (rule #21) so global_load_lds dest stays linear; reads de-swizzle.
#pragma unroll
    for (int s2 = 0; s2 < 4; ++s2) {
      int grp = s2 * 4 + w;
      int r = grp * 8 + lrow;
      int gch = lch ^ lrow;
      gload_lds16(A + (arow0 + r) * K + kt + gch * 8, &As[grp * 512]);
      gload_lds16(BT + (brow0 + r) * K + kt + gch * 8, &Bs[grp * 512]);
    }
    asm volatile("s_waitcnt vmcnt(0)" ::: "memory");
    __syncthreads();
#pragma unroll
    for (int kk = 0; kk < 2; ++kk) {
      bf16x8 af[4], bfr[4];
#pragma unroll
      for (int i = 0; i < 4; ++i) {
        int ra = wm * 64 + i * 16 + lq;
        af[i] = *(const bf16x8*)&As[ra * 64 + (((kk * 4 + lk) ^ (ra & 7)) * 8)];
        int rb = wn * 64 + i * 16 + lq;
        bfr[i] = *(const bf16x8*)&Bs[rb * 64 + (((kk * 4 + lk) ^ (rb & 7)) * 8)];
      }
#pragma unroll
      for (int i = 0; i < 4; ++i)
#pragma unroll
        for (int j = 0; j < 4; ++j)
          acc[i][j] = __builtin_amdgcn_mfma_f32_16x16x32_bf16(af[i], bfr[j],
                                                              acc[i][j], 0, 0, 0);
    }
  }
  (void)M;
  const int rbase = bm * 128 + wm * 64 + lk * 4;
  const int cbase = bn * 128 + wn * 64 + lq;
#pragma unroll
  for (int i = 0; i < 4; ++i) {
#pragma unroll
    for (int j = 0; j < 4; ++j) {
#pragma unroll
      for (int r2 = 0; r2 < 4; ++r2) {
        long row = rbase + i * 16 + r2;
        long col = cbase + j * 16;
        float v = acc[i][j][r2];
        if (EPI == 0)
          ((unsigned short*)Cout)[row * N + col] = f2bf(v);
        else if (EPI == 1)
          ((float*)Cout)[row * N + col] += v;
        else
          ((float*)Cout)[row * N + col] = v;
      }
    }
  }
}

extern "C" void kernel_launch(void* const* d_in, const int* in_sizes, int n_in,
                              void* d_out, int out_size, void* d_ws, size_t ws_size,
                              hipStream_t stream) {
  (void)in_sizes; (void)n_in; (void)out_size; (void)ws_size;
  const int* tokens   = (const int*)d_in[0];
  const float* tok_emb = (const float*)d_in[1];
  const float* pos_emb = (const float*)d_in[2];
  const float* dpb_w1 = (const float*)d_in[3];
  const float* dpb_b1 = (const float*)d_in[4];
  const float* dpb_w2 = (const float*)d_in[5];
  const float* dpb_b2 = (const float*)d_in[6];
  const float* dpb_w3 = (const float*)d_in[7];
  const float* dpb_b3 = (const float*)d_in[8];
  const float* ln1_g  = (const float*)d_in[9];
  const float* ln1_b  = (const float*)d_in[10];
  const float* Wqkv   = (const float*)d_in[11];
  const float* Wo     = (const float*)d_in[12];
  const float* ln2_g  = (const float*)d_in[13];
  const float* ln2_b  = (const float*)d_in[14];
  const float* Wff1   = (const float*)d_in[15];
  const float* Wff2   = (const float*)d_in[16];
  const float* lnf_g  = (const float*)d_in[17];
  const float* lnf_b  = (const float*)d_in[18];
  const float* Wlog   = (const float*)d_in[19];
  float* out = (float*)d_out;

  char* p = (char*)d_ws;
  auto carve = [&](size_t bytes) {
    char* q = p;
    p += (bytes + 255) & ~(size_t)255;
    return (void*)q;
  };
  unsigned short* WqkvT = (unsigned short*)carve((size_t)4 * 3072 * 1024 * 2);
  unsigned short* WoT   = (unsigned short*)carve((size_t)4 * 1024 * 1024 * 2);
  unsigned short* Wff1T = (unsigned short*)carve((size_t)4 * 5504 * 1024 * 2);
  unsigned short* Wff2T = (unsigned short*)carve((size_t)4 * 1024 * 2752 * 2);
  unsigned short* WlogT = (unsigned short*)carve((size_t)32000 * 1024 * 2);
  float*          x     = (float*)carve((size_t)2048 * 1024 * 4);
  unsigned short* hbuf  = (unsigned short*)carve((size_t)2048 * 1024 * 2);
  unsigned short* qkv   = (unsigned short*)carve((size_t)2048 * 3072 * 2);
  unsigned short* ao    = (unsigned short*)carve((size_t)2048 * 1024 * 2);
  unsigned short* ff    = (unsigned short*)carve((size_t)2048 * 5504 * 2);
  unsigned short* ubuf  = (unsigned short*)carve((size_t)2048 * 2752 * 2);
  float*          table = (float*)carve((size_t)1024 * 16 * 4);

  // weight convert + transpose (zero-padded ragged dims)
  k_wconv<<<dim3(3072 / 32, 1024 / 32, 4), 256, 0, stream>>>(
      Wqkv, WqkvT, 1024, 3072, 1024, 3072, (long)1024 * 3072, (long)3072 * 1024);
  k_wconv<<<dim3(1024 / 32, 1024 / 32, 4), 256, 0, stream>>>(
      Wo, WoT, 1024, 1024, 1024, 1024, (long)1024 * 1024, (long)1024 * 1024);
  k_wconv<<<dim3(5504 / 32, 1024 / 32, 4), 256, 0, stream>>>(
      Wff1, Wff1T, 1024, 5460, 1024, 5504, (long)1024 * 5460, (long)5504 * 1024);
  k_wconv<<<dim3(1024 / 32, 2752 / 32, 4), 256, 0, stream>>>(
      Wff2, Wff2T, 2730, 1024, 2752, 1024, (long)2730 * 1024, (long)1024 * 2752);
  k_wconv<<<dim3(32000 / 32, 1024 / 32, 1), 256, 0, stream>>>(
      Wlog, WlogT, 1024, 32000, 1024, 32000, 0L, 0L);

  k_dpb<<<1024, 256, 0, stream>>>(dpb_w1, dpb_b1, dpb_w2, dpb_b2, dpb_w3, dpb_b3, table);
  k_embed<<<2048, 256, 0, stream>>>(tokens, tok_emb, pos_emb, x);

  for (int l = 0; l < 4; ++l) {
    k_ln<<<2048, 256, 0, stream>>>(x, ln1_g + l * 1024, ln1_b + l * 1024, hbuf);
    k_gemm<0><<<dim3(3072 / 128, 16), 256, 0, stream>>>(
        hbuf, WqkvT + (long)l * 3072 * 1024, qkv, 2048, 3072, 1024);
    k_attn<<<dim3(64, 16, 4), 256, 0, stream>>>(qkv, table, ao);
    k_gemm<1><<<dim3(1024 / 128, 16), 256, 0, stream>>>(
        ao, WoT + (long)l * 1024 * 1024, x, 2048, 1024, 1024);
    k_ln<<<2048, 256, 0, stream>>>(x, ln2_g + l * 1024, ln2_b + l * 1024, hbuf);
    k_gemm<0><<<dim3(5504 / 128, 16), 256, 0, stream>>>(
        hbuf, Wff1T + (long)l * 5504 * 1024, ff, 2048, 5504, 1024);
    k_glu<<<2048, 256, 0, stream>>>(ff, ubuf);
    k_gemm<1><<<dim3(1024 / 128, 16), 256, 0, stream>>>(
        ubuf, Wff2T + (long)l * 1024 * 2752, x, 2048, 1024, 2752);
  }
  k_ln<<<2048, 256, 0, stream>>>(x, lnf_g, lnf_b, hbuf);
  k_gemm<2><<<dim3(32000 / 128, 16), 256, 0, stream>>>(
      hbuf, WlogT, out, 2048, 32000, 1024);
}

// Round 2
// 1234.947 us; speedup vs baseline: 2.5288x; 2.5288x over previous
//
#include <hip/hip_runtime.h>
#include <cstdint>

#define DEV __device__ __forceinline__

typedef __attribute__((ext_vector_type(8))) short bf16x8;
typedef __attribute__((ext_vector_type(4))) short bf16x4;
typedef __attribute__((ext_vector_type(4))) float f32x4;

DEV float bf2f(unsigned short u) { return __uint_as_float(((unsigned)u) << 16); }
DEV unsigned short f2bf(float f) {
  unsigned u = __float_as_uint(f);
  u += 0x7FFFu + ((u >> 16) & 1u);
  return (unsigned short)(u >> 16);
}

DEV void gload_lds16(const void* g, void* lds) {
  __builtin_amdgcn_global_load_lds(
      (const __attribute__((address_space(1))) unsigned int*)g,
      (__attribute__((address_space(3))) unsigned int*)lds, 16, 0, 0);
}

// ---------------- embedding: x = tok_emb[tok] + pos_emb ----------------
__global__ __launch_bounds__(256) void k_embed(const int* __restrict__ tokens,
    const float* __restrict__ tok_emb, const float* __restrict__ pos_emb,
    float* __restrict__ x) {
  int n = blockIdx.x;
  int tok = tokens[n];
  int c = threadIdx.x * 4;
  float4 a = *(const float4*)(tok_emb + (long)tok * 1024 + c);
  float4 p = *(const float4*)(pos_emb + (long)n * 1024 + c);
  float4 r;
  r.x = a.x + p.x; r.y = a.y + p.y; r.z = a.z + p.z; r.w = a.w + p.w;
  *(float4*)(x + (long)n * 1024 + c) = r;
}

// ---------------- layernorm (fp32 in) -> bf16 out ----------------
__global__ __launch_bounds__(256) void k_ln(const float* __restrict__ x,
    const float* __restrict__ g, const float* __restrict__ b,
    unsigned short* __restrict__ out) {
  __shared__ float red[8];
  int row = blockIdx.x, t = threadIdx.x;
  const float* xr = x + (long)row * 1024;
  float4 v = *(const float4*)(xr + t * 4);
  float s = v.x + v.y + v.z + v.w;
#pragma unroll
  for (int off = 32; off; off >>= 1) s += __shfl_xor(s, off);
  if ((t & 63) == 0) red[t >> 6] = s;
  __syncthreads();
  float mean = (red[0] + red[1] + red[2] + red[3]) * (1.0f / 1024.0f);
  float dx = v.x - mean, dy = v.y - mean, dz = v.z - mean, dw = v.w - mean;
  float sq = dx * dx + dy * dy + dz * dz + dw * dw;
#pragma unroll
  for (int off = 32; off; off >>= 1) sq += __shfl_xor(sq, off);
  if ((t & 63) == 0) red[4 + (t >> 6)] = sq;
  __syncthreads();
  float var = (red[4] + red[5] + red[6] + red[7]) * (1.0f / 1024.0f);
  float inv = rsqrtf(var + 1e-5f);
  int c = t * 4;
  float4 gv = *(const float4*)(g + c);
  float4 bv = *(const float4*)(b + c);
  ushort4 o;
  o.x = f2bf(dx * inv * gv.x + bv.x);
  o.y = f2bf(dy * inv * gv.y + bv.y);
  o.z = f2bf(dz * inv * gv.z + bv.z);
  o.w = f2bf(dw * inv * gv.w + bv.w);
  *(ushort4*)(out + (long)row * 1024 + c) = o;
}

// ---------------- weight fp32 (K,N) -> bf16 W^T (Np,Kp), zero-padded ----------------
__global__ __launch_bounds__(256) void k_wconv(const float* __restrict__ src,
    unsigned short* __restrict__ dst, int K, int N, int Kp, int Np,
    long sstride, long dstride) {
  __shared__ float tile[32][33];
  const float* s = src + (long)blockIdx.z * sstride;
  unsigned short* d = dst + (long)blockIdx.z * dstride;
  int n0 = blockIdx.x * 32, k0 = blockIdx.y * 32;
  int t = threadIdx.x;
  int r = t >> 3, c4 = (t & 7) * 4;
  int k = k0 + r;
#pragma unroll
  for (int e = 0; e < 4; ++e) {
    int n = n0 + c4 + e;
    tile[r][c4 + e] = (k < K && n < N) ? s[(long)k * N + n] : 0.0f;
  }
  __syncthreads();
  int nrow = n0 + r;
  ushort4 o;
  o.x = f2bf(tile[c4 + 0][r]);
  o.y = f2bf(tile[c4 + 1][r]);
  o.z = f2bf(tile[c4 + 2][r]);
  o.w = f2bf(tile[c4 + 3][r]);
  (void)Np;
  *(ushort4*)(d + (long)nrow * Kp + k0 + c4) = o;
}

// ---------------- dynamic position bias table: table[rel(0..1023)][head(0..15)] ----------------
__global__ __launch_bounds__(256) void k_dpb(const float* __restrict__ w1,
    const float* __restrict__ b1, const float* __restrict__ w2,
    const float* __restrict__ b2, const float* __restrict__ w3,
    const float* __restrict__ b3, float* __restrict__ table) {
  __shared__ float h1[512], h2[512];
  int r = blockIdx.x, t = threadIdx.x;
  float rf = (float)r;
  for (int c = t; c < 512; c += 256) {
    float v = rf * w1[c] + b1[c];
    h1[c] = v / (1.0f + __expf(-v));  // silu
  }
  __syncthreads();
  for (int c = t; c < 512; c += 256) {
    float acc = b2[c];
    for (int k2 = 0; k2 < 512; ++k2) acc = fmaf(h1[k2], w2[(long)k2 * 512 + c], acc);
    h2[c] = acc / (1.0f + __expf(-acc));
  }
  __syncthreads();
  if (t < 16) {
    float acc = b3[t];
    for (int k2 = 0; k2 < 512; ++k2) acc = fmaf(h2[k2], w3[k2 * 16 + t], acc);
    table[r * 16 + t] = acc;
  }
}

// ---------------- GLU: u = a * gelu_exact(gate), zero-padded to 2752 ----------------
__global__ __launch_bounds__(256) void k_glu(const unsigned short* __restrict__ ff,
    unsigned short* __restrict__ u) {
  int row = blockIdx.x, t = threadIdx.x;
  const unsigned short* fr = ff + (long)row * 5504;
  unsigned short* ur = u + (long)row * 2752;
  for (int c = t; c < 2752; c += 256) {
    float val = 0.0f;
    if (c < 2730) {
      float a = bf2f(fr[c]);
      float gt = bf2f(fr[2730 + c]);
      val = a * (0.5f * gt * (1.0f + erff(gt * 0.70710678118654752f)));
    }
    ur[c] = f2bf(val);
  }
}

// ---------------- MFMA flash local attention ----------------
// grid (8 qtiles, 16 heads, 4 windows), 256 threads = 4 waves, wave owns 16 q rows.
// qkv layout: (n, [q|k|v] each 1024) bf16. key index jj in [0,1024) maps to
// global key (wi-1)*512+jj. allowed: jj>=iw && jj<=iw+512 && (wi>0 || jj>=512).
__global__ __launch_bounds__(256, 2) void k_attn_mfma(
    const unsigned short* __restrict__ qkv, const float* __restrict__ table,
    unsigned short* __restrict__ o) {
  __shared__ unsigned short Ks[64 * 64];      // swizzled rows (key), 8 chunks of 8
  __shared__ unsigned short Vt[64 * 72];      // Vt[d][key], stride 72
  __shared__ unsigned short Ps[4][16 * 72];   // per-wave P, stride 72
  __shared__ float biasl[1024];
  const int qt = blockIdx.x, h = blockIdx.y, wi = blockIdx.z;
  const int iw0 = qt * 64;
  const int t = threadIdx.x;
  const int w = t >> 6, l = t & 63;
  const int lq = l & 15, lk = l >> 4;

  for (int i = t; i < 1024; i += 256) biasl[i] = table[i * 16 + h];

  // Q fragments for this wave's 16 rows
  const unsigned short* qp = qkv + (long)(wi * 512 + iw0 + w * 16 + lq) * 3072 + h * 64;
  bf16x8 qf0 = *(const bf16x8*)(qp + lk * 8);
  bf16x8 qf1 = *(const bf16x8*)(qp + 32 + lk * 8);

  f32x4 oacc[4] = {};
  float mrun[4] = {-3.0e38f, -3.0e38f, -3.0e38f, -3.0e38f};
  float srun[4] = {};

  const int kt0 = (wi == 0) ? 8 : qt;
  const int kt1 = qt + 8;
  for (int kt = kt0; kt <= kt1; ++kt) {
    const int ktbase = kt * 64;
    const long kgbase = (long)((wi - 1) * 512 + ktbase);
    __syncthreads();  // all waves done with previous Ks/Vt
    // stage K (64 keys x 64 d), XOR-swizzled global source, linear LDS dest
    {
      const unsigned short* Kg = qkv + kgbase * 3072 + 1024 + h * 64;
#pragma unroll
      for (int s2 = 0; s2 < 2; ++s2) {
        int g = s2 * 4 + w;
        int row = g * 8 + (l >> 3);
        int gch = (l & 7) ^ (row & 7);
        gload_lds16(Kg + (long)row * 3072 + gch * 8, &Ks[g * 512]);
      }
    }
    // stage V transposed: Vt[d][key]
    {
      int kp = t & 31, dg = t >> 5;  // kp: key pair, dg: 8-dim group
      const unsigned short* Vg =
          qkv + (kgbase + 2 * kp) * 3072 + 2048 + h * 64 + dg * 8;
      bf16x8 a0 = *(const bf16x8*)Vg;
      bf16x8 a1 = *(const bf16x8*)(Vg + 3072);
#pragma unroll
      for (int e = 0; e < 8; ++e) {
        unsigned pack = ((unsigned)(unsigned short)a0[e]) |
                        (((unsigned)(unsigned short)a1[e]) << 16);
        *(unsigned*)&Vt[(dg * 8 + e) * 72 + 2 * kp] = pack;
      }
    }
    asm volatile("s_waitcnt vmcnt(0)" ::: "memory");
    __syncthreads();

    // QK^T: S[16 q x 64 keys] per wave
    f32x4 sacc[4] = {};
#pragma unroll
    for (int ct = 0; ct < 4; ++ct) {
      int krow = ct * 16 + lq;
      bf16x8 kf0 = *(const bf16x8*)&Ks[krow * 64 + (((0 + lk) ^ (krow & 7)) * 8)];
      bf16x8 kf1 = *(const bf16x8*)&Ks[krow * 64 + (((4 + lk) ^ (krow & 7)) * 8)];
      sacc[ct] = __builtin_amdgcn_mfma_f32_16x16x32_bf16(qf0, kf0, sacc[ct], 0, 0, 0);
      sacc[ct] = __builtin_amdgcn_mfma_f32_16x16x32_bf16(qf1, kf1, sacc[ct], 0, 0, 0);
    }

    // scale + bias + mask + online softmax; write P to per-wave LDS
#pragma unroll
    for (int r = 0; r < 4; ++r) {
      const int iw = iw0 + w * 16 + lk * 4 + r;
      float sc[4];
#pragma unroll
      for (int ct = 0; ct < 4; ++ct) {
        int jj = ktbase + ct * 16 + lq;
        int di = 512 + iw - jj;
        int dic = min(max(di, 0), 1023);
        bool allowed = (jj >= iw) && (jj <= iw + 512);
        float v = sacc[ct][r] * 0.125f + biasl[dic];
        sc[ct] = allowed ? v : -3.0e38f;
      }
      float mx = fmaxf(fmaxf(sc[0], sc[1]), fmaxf(sc[2], sc[3]));
      mx = fmaxf(mx, __shfl_xor(mx, 1));
      mx = fmaxf(mx, __shfl_xor(mx, 2));
      mx = fmaxf(mx, __shfl_xor(mx, 4));
      mx = fmaxf(mx, __shfl_xor(mx, 8));
      float mnew = fmaxf(mrun[r], mx);
      float f = __expf(mrun[r] - mnew);
      mrun[r] = mnew;
      float rs = 0.0f;
#pragma unroll
      for (int ct = 0; ct < 4; ++ct) {
        float pv = __expf(sc[ct] - mnew);
        rs += pv;
        Ps[w][(lk * 4 + r) * 72 + ct * 16 + lq] = f2bf(pv);
      }
      rs += __shfl_xor(rs, 1);
      rs += __shfl_xor(rs, 2);
      rs += __shfl_xor(rs, 4);
      rs += __shfl_xor(rs, 8);
      srun[r] = srun[r] * f + rs;
#pragma unroll
      for (int dt = 0; dt < 4; ++dt) oacc[dt][r] *= f;
    }
    asm volatile("s_waitcnt lgkmcnt(0)" ::: "memory");

    // PV: O[16 q x 64 d] += P(16x64) * V(64x64)
#pragma unroll
    for (int ks = 0; ks < 2; ++ks) {
      bf16x4 pa0 = *(const bf16x4*)&Ps[w][lq * 72 + ks * 32 + lk * 8];
      bf16x4 pa1 = *(const bf16x4*)&Ps[w][lq * 72 + ks * 32 + lk * 8 + 4];
      bf16x8 pa = __builtin_shufflevector(pa0, pa1, 0, 1, 2, 3, 4, 5, 6, 7);
#pragma unroll
      for (int dt = 0; dt < 4; ++dt) {
        int drow = dt * 16 + lq;
        bf16x4 vb0 = *(const bf16x4*)&Vt[drow * 72 + ks * 32 + lk * 8];
        bf16x4 vb1 = *(const bf16x4*)&Vt[drow * 72 + ks * 32 + lk * 8 + 4];
        bf16x8 vb = __builtin_shufflevector(vb0, vb1, 0, 1, 2, 3, 4, 5, 6, 7);
        oacc[dt] = __builtin_amdgcn_mfma_f32_16x16x32_bf16(pa, vb, oacc[dt], 0, 0, 0);
      }
    }
  }

  // epilogue: normalize and store
  unsigned short* ob =
      o + (long)(wi * 512 + iw0 + w * 16 + lk * 4) * 1024 + h * 64 + lq;
#pragma unroll
  for (int r = 0; r < 4; ++r) {
    float inv = 1.0f / srun[r];
#pragma unroll
    for (int dt = 0; dt < 4; ++dt)
      ob[(long)r * 1024 + dt * 16] = f2bf(oacc[dt][r] * inv);
  }
}

// ---------------- GEMM: C(M,N) = A(M,K) * B^T(N,K), bf16 MFMA ----------------
// EPI: 0 = store bf16, 1 = fp32 +=, 2 = store fp32
template <int EPI>
__global__ __launch_bounds__(256, 2) void k_gemm(const unsigned short* __restrict__ A,
    const unsigned short* __restrict__ BT, void* __restrict__ Cout,
    int M, int N, int K) {
  __shared__ unsigned short As[128 * 64];
  __shared__ unsigned short Bs[128 * 64];
  const int bn = blockIdx.x, bm = blockIdx.y;
  const int t = threadIdx.x;
  const int w = t >> 6, l = t & 63;
  const int wm = w >> 1, wn = w & 1;   // 2x2 waves, 64x64 each
  const int lrow = l >> 3, lch = l & 7;
  const int lq = l & 15, lk = l >> 4;
  f32x4 acc[4][4] = {};
  const long arow0 = (long)bm * 128, brow0 = (long)bn * 128;
  for (int kt = 0; kt < K; kt += 64) {
    __syncthreads();
#pragma unroll
    for (int s2 = 0; s2 < 4; ++s2) {
      int grp = s2 * 4 + w;
      int r = grp * 8 + lrow;
      int gch = lch ^ lrow;
      gload_lds16(A + (arow0 + r) * K + kt + gch * 8, &As[grp * 512]);
      gload_lds16(BT + (brow0 + r) * K + kt + gch * 8, &Bs[grp * 512]);
    }
    asm volatile("s_waitcnt vmcnt(0)" ::: "memory");
    __syncthreads();
#pragma unroll
    for (int kk = 0; kk < 2; ++kk) {
      bf16x8 af[4], bfr[4];
#pragma unroll
      for (int i = 0; i < 4; ++i) {
        int ra = wm * 64 + i * 16 + lq;
        af[i] = *(const bf16x8*)&As[ra * 64 + (((kk * 4 + lk) ^ (ra & 7)) * 8)];
        int rb = wn * 64 + i * 16 + lq;
        bfr[i] = *(const bf16x8*)&Bs[rb * 64 + (((kk * 4 + lk) ^ (rb & 7)) * 8)];
      }
#pragma unroll
      for (int i = 0; i < 4; ++i)
#pragma unroll
        for (int j = 0; j < 4; ++j)
          acc[i][j] = __builtin_amdgcn_mfma_f32_16x16x32_bf16(af[i], bfr[j],
                                                              acc[i][j], 0, 0, 0);
    }
  }
  (void)M;
  const int rbase = bm * 128 + wm * 64 + lk * 4;
  const int cbase = bn * 128 + wn * 64 + lq;
#pragma unroll
  for (int i = 0; i < 4; ++i) {
#pragma unroll
    for (int j = 0; j < 4; ++j) {
#pragma unroll
      for (int r2 = 0; r2 < 4; ++r2) {
        long row = rbase + i * 16 + r2;
        long col = cbase + j * 16;
        float v = acc[i][j][r2];
        if (EPI == 0)
          ((unsigned short*)Cout)[row * N + col] = f2bf(v);
        else if (EPI == 1)
          ((float*)Cout)[row * N + col] += v;
        else
          ((float*)Cout)[row * N + col] = v;
      }
    }
  }
}

extern "C" void kernel_launch(void* const* d_in, const int* in_sizes, int n_in,
                              void* d_out, int out_size, void* d_ws, size_t ws_size,
                              hipStream_t stream) {
  (void)in_sizes; (void)n_in; (void)out_size; (void)ws_size;
  const int* tokens   = (const int*)d_in[0];
  const float* tok_emb = (const float*)d_in[1];
  const float* pos_emb = (const float*)d_in[2];
  const float* dpb_w1 = (const float*)d_in[3];
  const float* dpb_b1 = (const float*)d_in[4];
  const float* dpb_w2 = (const float*)d_in[5];
  const float* dpb_b2 = (const float*)d_in[6];
  const float* dpb_w3 = (const float*)d_in[7];
  const float* dpb_b3 = (const float*)d_in[8];
  const float* ln1_g  = (const float*)d_in[9];
  const float* ln1_b  = (const float*)d_in[10];
  const float* Wqkv   = (const float*)d_in[11];
  const float* Wo     = (const float*)d_in[12];
  const float* ln2_g  = (const float*)d_in[13];
  const float* ln2_b  = (const float*)d_in[14];
  const float* Wff1   = (const float*)d_in[15];
  const float* Wff2   = (const float*)d_in[16];
  const float* lnf_g  = (const float*)d_in[17];
  const float* lnf_b  = (const float*)d_in[18];
  const float* Wlog   = (const float*)d_in[19];
  float* out = (float*)d_out;

  char* p = (char*)d_ws;
  auto carve = [&](size_t bytes) {
    char* q = p;
    p += (bytes + 255) & ~(size_t)255;
    return (void*)q;
  };
  unsigned short* WqkvT = (unsigned short*)carve((size_t)4 * 3072 * 1024 * 2);
  unsigned short* WoT   = (unsigned short*)carve((size_t)4 * 1024 * 1024 * 2);
  unsigned short* Wff1T = (unsigned short*)carve((size_t)4 * 5504 * 1024 * 2);
  unsigned short* Wff2T = (unsigned short*)carve((size_t)4 * 1024 * 2752 * 2);
  unsigned short* WlogT = (unsigned short*)carve((size_t)32000 * 1024 * 2);
  float*          x     = (float*)carve((size_t)2048 * 1024 * 4);
  unsigned short* hbuf  = (unsigned short*)carve((size_t)2048 * 1024 * 2);
  unsigned short* qkv   = (unsigned short*)carve((size_t)2048 * 3072 * 2);
  unsigned short* ao    = (unsigned short*)carve((size_t)2048 * 1024 * 2);
  unsigned short* ff    = (unsigned short*)carve((size_t)2048 * 5504 * 2);
  unsigned short* ubuf  = (unsigned short*)carve((size_t)2048 * 2752 * 2);
  float*          table = (float*)carve((size_t)1024 * 16 * 4);

  k_wconv<<<dim3(3072 / 32, 1024 / 32, 4), 256, 0, stream>>>(
      Wqkv, WqkvT, 1024, 3072, 1024, 3072, (long)1024 * 3072, (long)3072 * 1024);
  k_wconv<<<dim3(1024 / 32, 1024 / 32, 4), 256, 0, stream>>>(
      Wo, WoT, 1024, 1024, 1024, 1024, (long)1024 * 1024, (long)1024 * 1024);
  k_wconv<<<dim3(5504 / 32, 1024 / 32, 4), 256, 0, stream>>>(
      Wff1, Wff1T, 1024, 5460, 1024, 5504, (long)1024 * 5460, (long)5504 * 1024);
  k_wconv<<<dim3(1024 / 32, 2752 / 32, 4), 256, 0, stream>>>(
      Wff2, Wff2T, 2730, 1024, 2752, 1024, (long)2730 * 1024, (long)1024 * 2752);
  k_wconv<<<dim3(32000 / 32, 1024 / 32, 1), 256, 0, stream>>>(
      Wlog, WlogT, 1024, 32000, 1024, 32000, 0L, 0L);

  k_dpb<<<1024, 256, 0, stream>>>(dpb_w1, dpb_b1, dpb_w2, dpb_b2, dpb_w3, dpb_b3, table);
  k_embed<<<2048, 256, 0, stream>>>(tokens, tok_emb, pos_emb, x);

  for (int l = 0; l < 4; ++l) {
    k_ln<<<2048, 256, 0, stream>>>(x, ln1_g + l * 1024, ln1_b + l * 1024, hbuf);
    k_gemm<0><<<dim3(3072 / 128, 16), 256, 0, stream>>>(
        hbuf, WqkvT + (long)l * 3072 * 1024, qkv, 2048, 3072, 1024);
    k_attn_mfma<<<dim3(8, 16, 4), 256, 0, stream>>>(qkv, table, ao);
    k_gemm<1><<<dim3(1024 / 128, 16), 256, 0, stream>>>(
        ao, WoT + (long)l * 1024 * 1024, x, 2048, 1024, 1024);
    k_ln<<<2048, 256, 0, stream>>>(x, ln2_g + l * 1024, ln2_b + l * 1024, hbuf);
    k_gemm<0><<<dim3(5504 / 128, 16), 256, 0, stream>>>(
        hbuf, Wff1T + (long)l * 5504 * 1024, ff, 2048, 5504, 1024);
    k_glu<<<2048, 256, 0, stream>>>(ff, ubuf);
    k_gemm<1><<<dim3(1024 / 128, 16), 256, 0, stream>>>(
        ubuf, Wff2T + (long)l * 1024 * 2752, x, 2048, 1024, 2752);
  }
  k_ln<<<2048, 256, 0, stream>>>(x, lnf_g, lnf_b, hbuf);
  k_gemm<2><<<dim3(32000 / 128, 16), 256, 0, stream>>>(
      hbuf, WlogT, out, 2048, 32000, 1024);
}

// Round 3
// 1182.502 us; speedup vs baseline: 2.6409x; 1.0444x over previous
//
#include <hip/hip_runtime.h>
#include <cstdint>

#define DEV __device__ __forceinline__

typedef __attribute__((ext_vector_type(8))) short bf16x8;
typedef __attribute__((ext_vector_type(4))) short bf16x4;
typedef __attribute__((ext_vector_type(4))) float f32x4;

DEV float bf2f(unsigned short u) { return __uint_as_float(((unsigned)u) << 16); }
DEV unsigned short f2bf(float f) {
  unsigned u = __float_as_uint(f);
  u += 0x7FFFu + ((u >> 16) & 1u);
  return (unsigned short)(u >> 16);
}

DEV void gload_lds16(const void* g, void* lds) {
  __builtin_amdgcn_global_load_lds(
      (const __attribute__((address_space(1))) unsigned int*)g,
      (__attribute__((address_space(3))) unsigned int*)lds, 16, 0, 0);
}

// ---------------- embedding: x = tok_emb[tok] + pos_emb ----------------
__global__ __launch_bounds__(256) void k_embed(const int* __restrict__ tokens,
    const float* __restrict__ tok_emb, const float* __restrict__ pos_emb,
    float* __restrict__ x) {
  int n = blockIdx.x;
  int tok = tokens[n];
  int c = threadIdx.x * 4;
  float4 a = *(const float4*)(tok_emb + (long)tok * 1024 + c);
  float4 p = *(const float4*)(pos_emb + (long)n * 1024 + c);
  float4 r;
  r.x = a.x + p.x; r.y = a.y + p.y; r.z = a.z + p.z; r.w = a.w + p.w;
  *(float4*)(x + (long)n * 1024 + c) = r;
}

// ---------------- layernorm (fp32 in) -> bf16 out ----------------
__global__ __launch_bounds__(256) void k_ln(const float* __restrict__ x,
    const float* __restrict__ g, const float* __restrict__ b,
    unsigned short* __restrict__ out) {
  __shared__ float red[8];
  int row = blockIdx.x, t = threadIdx.x;
  const float* xr = x + (long)row * 1024;
  float4 v = *(const float4*)(xr + t * 4);
  float s = v.x + v.y + v.z + v.w;
#pragma unroll
  for (int off = 32; off; off >>= 1) s += __shfl_xor(s, off);
  if ((t & 63) == 0) red[t >> 6] = s;
  __syncthreads();
  float mean = (red[0] + red[1] + red[2] + red[3]) * (1.0f / 1024.0f);
  float dx = v.x - mean, dy = v.y - mean, dz = v.z - mean, dw = v.w - mean;
  float sq = dx * dx + dy * dy + dz * dz + dw * dw;
#pragma unroll
  for (int off = 32; off; off >>= 1) sq += __shfl_xor(sq, off);
  if ((t & 63) == 0) red[4 + (t >> 6)] = sq;
  __syncthreads();
  float var = (red[4] + red[5] + red[6] + red[7]) * (1.0f / 1024.0f);
  float inv = rsqrtf(var + 1e-5f);
  int c = t * 4;
  float4 gv = *(const float4*)(g + c);
  float4 bv = *(const float4*)(b + c);
  ushort4 o;
  o.x = f2bf(dx * inv * gv.x + bv.x);
  o.y = f2bf(dy * inv * gv.y + bv.y);
  o.z = f2bf(dz * inv * gv.z + bv.z);
  o.w = f2bf(dw * inv * gv.w + bv.w);
  *(ushort4*)(out + (long)row * 1024 + c) = o;
}

// ---------------- weight fp32 (K,N) -> bf16 W^T (Np,Kp), zero-padded ----------------
__global__ __launch_bounds__(256) void k_wconv(const float* __restrict__ src,
    unsigned short* __restrict__ dst, int K, int N, int Kp, int Np,
    long sstride, long dstride) {
  __shared__ float tile[32][33];
  const float* s = src + (long)blockIdx.z * sstride;
  unsigned short* d = dst + (long)blockIdx.z * dstride;
  int n0 = blockIdx.x * 32, k0 = blockIdx.y * 32;
  int t = threadIdx.x;
  int r = t >> 3, c4 = (t & 7) * 4;
  int k = k0 + r, n = n0 + c4;
  float4 v = make_float4(0.f, 0.f, 0.f, 0.f);
  if (k < K && n < N) v = *(const float4*)(s + (long)k * N + n);  // N%4==0 always
  tile[r][c4 + 0] = v.x;
  tile[r][c4 + 1] = v.y;
  tile[r][c4 + 2] = v.z;
  tile[r][c4 + 3] = v.w;
  __syncthreads();
  int nrow = n0 + r;
  ushort4 o;
  o.x = f2bf(tile[c4 + 0][r]);
  o.y = f2bf(tile[c4 + 1][r]);
  o.z = f2bf(tile[c4 + 2][r]);
  o.w = f2bf(tile[c4 + 3][r]);
  (void)Np;
  *(ushort4*)(d + (long)nrow * Kp + k0 + c4) = o;
}

// ---------------- dynamic position bias table: table[rel(0..1023)][head(0..15)] ----------------
__global__ __launch_bounds__(256) void k_dpb(const float* __restrict__ w1,
    const float* __restrict__ b1, const float* __restrict__ w2,
    const float* __restrict__ b2, const float* __restrict__ w3,
    const float* __restrict__ b3, float* __restrict__ table) {
  __shared__ float h1[512], h2[512];
  int r = blockIdx.x, t = threadIdx.x;
  float rf = (float)r;
  for (int c = t; c < 512; c += 256) {
    float v = rf * w1[c] + b1[c];
    h1[c] = v / (1.0f + __expf(-v));  // silu
  }
  __syncthreads();
  for (int c = t; c < 512; c += 256) {
    float acc = b2[c];
    for (int k2 = 0; k2 < 512; ++k2) acc = fmaf(h1[k2], w2[(long)k2 * 512 + c], acc);
    h2[c] = acc / (1.0f + __expf(-acc));
  }
  __syncthreads();
  if (t < 16) {
    float acc = b3[t];
    for (int k2 = 0; k2 < 512; ++k2) acc = fmaf(h2[k2], w3[k2 * 16 + t], acc);
    table[r * 16 + t] = acc;
  }
}

// ---------------- GLU: u = a * gelu_exact(gate), zero-padded to 2752 ----------------
__global__ __launch_bounds__(256) void k_glu(const unsigned short* __restrict__ ff,
    unsigned short* __restrict__ u) {
  int row = blockIdx.x, t = threadIdx.x;
  const unsigned short* fr = ff + (long)row * 5504;
  unsigned short* ur = u + (long)row * 2752;
  for (int c = t * 4; c < 2752; c += 1024) {
    ushort4 av = *(const ushort4*)(fr + c);            // 8B aligned
    ushort2 g0 = *(const ushort2*)(fr + 2730 + c);     // 4B aligned
    ushort2 g1 = *(const ushort2*)(fr + 2730 + c + 2);
    float aa[4] = {bf2f(av.x), bf2f(av.y), bf2f(av.z), bf2f(av.w)};
    float gg[4] = {bf2f(g0.x), bf2f(g0.y), bf2f(g1.x), bf2f(g1.y)};
    ushort4 o;
    unsigned short* op = (unsigned short*)&o;
#pragma unroll
    for (int e = 0; e < 4; ++e) {
      float val = 0.0f;
      if (c + e < 2730)
        val = aa[e] * (0.5f * gg[e] * (1.0f + erff(gg[e] * 0.70710678118654752f)));
      op[e] = f2bf(val);
    }
    *(ushort4*)(ur + c) = o;
  }
}

// ---------------- MFMA flash local attention ----------------
__global__ __launch_bounds__(256, 2) void k_attn_mfma(
    const unsigned short* __restrict__ qkv, const float* __restrict__ table,
    unsigned short* __restrict__ o) {
  __shared__ unsigned short Ks[64 * 64];      // swizzled rows (key), 8 chunks of 8
  __shared__ unsigned short Vt[64 * 72];      // Vt[d][key], stride 72
  __shared__ unsigned short Ps[4][16 * 72];   // per-wave P, stride 72
  __shared__ float biasl[1024];
  const int qt = blockIdx.x, h = blockIdx.y, wi = blockIdx.z;
  const int iw0 = qt * 64;
  const int t = threadIdx.x;
  const int w = t >> 6, l = t & 63;
  const int lq = l & 15, lk = l >> 4;

  for (int i = t; i < 1024; i += 256) biasl[i] = table[i * 16 + h];

  const unsigned short* qp = qkv + (long)(wi * 512 + iw0 + w * 16 + lq) * 3072 + h * 64;
  bf16x8 qf0 = *(const bf16x8*)(qp + lk * 8);
  bf16x8 qf1 = *(const bf16x8*)(qp + 32 + lk * 8);

  f32x4 oacc[4] = {};
  float mrun[4] = {-3.0e38f, -3.0e38f, -3.0e38f, -3.0e38f};
  float srun[4] = {};

  const int kt0 = (wi == 0) ? 8 : qt;
  const int kt1 = qt + 8;
  for (int kt = kt0; kt <= kt1; ++kt) {
    const int ktbase = kt * 64;
    const long kgbase = (long)((wi - 1) * 512 + ktbase);
    __syncthreads();
    {
      const unsigned short* Kg = qkv + kgbase * 3072 + 1024 + h * 64;
#pragma unroll
      for (int s2 = 0; s2 < 2; ++s2) {
        int g = s2 * 4 + w;
        int row = g * 8 + (l >> 3);
        int gch = (l & 7) ^ (row & 7);
        gload_lds16(Kg + (long)row * 3072 + gch * 8, &Ks[g * 512]);
      }
    }
    {
      int kp = t & 31, dg = t >> 5;
      const unsigned short* Vg =
          qkv + (kgbase + 2 * kp) * 3072 + 2048 + h * 64 + dg * 8;
      bf16x8 a0 = *(const bf16x8*)Vg;
      bf16x8 a1 = *(const bf16x8*)(Vg + 3072);
#pragma unroll
      for (int e = 0; e < 8; ++e) {
        unsigned pack = ((unsigned)(unsigned short)a0[e]) |
                        (((unsigned)(unsigned short)a1[e]) << 16);
        *(unsigned*)&Vt[(dg * 8 + e) * 72 + 2 * kp] = pack;
      }
    }
    asm volatile("s_waitcnt vmcnt(0)" ::: "memory");
    __syncthreads();

    f32x4 sacc[4] = {};
#pragma unroll
    for (int ct = 0; ct < 4; ++ct) {
      int krow = ct * 16 + lq;
      bf16x8 kf0 = *(const bf16x8*)&Ks[krow * 64 + (((0 + lk) ^ (krow & 7)) * 8)];
      bf16x8 kf1 = *(const bf16x8*)&Ks[krow * 64 + (((4 + lk) ^ (krow & 7)) * 8)];
      sacc[ct] = __builtin_amdgcn_mfma_f32_16x16x32_bf16(qf0, kf0, sacc[ct], 0, 0, 0);
      sacc[ct] = __builtin_amdgcn_mfma_f32_16x16x32_bf16(qf1, kf1, sacc[ct], 0, 0, 0);
    }

#pragma unroll
    for (int r = 0; r < 4; ++r) {
      const int iw = iw0 + w * 16 + lk * 4 + r;
      float sc[4];
#pragma unroll
      for (int ct = 0; ct < 4; ++ct) {
        int jj = ktbase + ct * 16 + lq;
        int di = 512 + iw - jj;
        int dic = min(max(di, 0), 1023);
        bool allowed = (jj >= iw) && (jj <= iw + 512);
        float v = sacc[ct][r] * 0.125f + biasl[dic];
        sc[ct] = allowed ? v : -3.0e38f;
      }
      float mx = fmaxf(fmaxf(sc[0], sc[1]), fmaxf(sc[2], sc[3]));
      mx = fmaxf(mx, __shfl_xor(mx, 1));
      mx = fmaxf(mx, __shfl_xor(mx, 2));
      mx = fmaxf(mx, __shfl_xor(mx, 4));
      mx = fmaxf(mx, __shfl_xor(mx, 8));
      float mnew = fmaxf(mrun[r], mx);
      float f = __expf(mrun[r] - mnew);
      mrun[r] = mnew;
      float rs = 0.0f;
#pragma unroll
      for (int ct = 0; ct < 4; ++ct) {
        float pv = __expf(sc[ct] - mnew);
        rs += pv;
        Ps[w][(lk * 4 + r) * 72 + ct * 16 + lq] = f2bf(pv);
      }
      rs += __shfl_xor(rs, 1);
      rs += __shfl_xor(rs, 2);
      rs += __shfl_xor(rs, 4);
      rs += __shfl_xor(rs, 8);
      srun[r] = srun[r] * f + rs;
#pragma unroll
      for (int dt = 0; dt < 4; ++dt) oacc[dt][r] *= f;
    }
    asm volatile("s_waitcnt lgkmcnt(0)" ::: "memory");

#pragma unroll
    for (int ks = 0; ks < 2; ++ks) {
      bf16x4 pa0 = *(const bf16x4*)&Ps[w][lq * 72 + ks * 32 + lk * 8];
      bf16x4 pa1 = *(const bf16x4*)&Ps[w][lq * 72 + ks * 32 + lk * 8 + 4];
      bf16x8 pa = __builtin_shufflevector(pa0, pa1, 0, 1, 2, 3, 4, 5, 6, 7);
#pragma unroll
      for (int dt = 0; dt < 4; ++dt) {
        int drow = dt * 16 + lq;
        bf16x4 vb0 = *(const bf16x4*)&Vt[drow * 72 + ks * 32 + lk * 8];
        bf16x4 vb1 = *(const bf16x4*)&Vt[drow * 72 + ks * 32 + lk * 8 + 4];
        bf16x8 vb = __builtin_shufflevector(vb0, vb1, 0, 1, 2, 3, 4, 5, 6, 7);
        oacc[dt] = __builtin_amdgcn_mfma_f32_16x16x32_bf16(pa, vb, oacc[dt], 0, 0, 0);
      }
    }
  }

  unsigned short* ob =
      o + (long)(wi * 512 + iw0 + w * 16 + lk * 4) * 1024 + h * 64 + lq;
#pragma unroll
  for (int r = 0; r < 4; ++r) {
    float inv = 1.0f / srun[r];
#pragma unroll
    for (int dt = 0; dt < 4; ++dt)
      ob[(long)r * 1024 + dt * 16] = f2bf(oacc[dt][r] * inv);
  }
}

// ---------------- GEMM: C(M,N) = A(M,K) * B^T(N,K), bf16 MFMA ----------------
// 1D grid, bm-fast ordering + bijective XCD swizzle (m204) for B-panel L2 reuse.
// EPI: 0 = store bf16, 1 = fp32 +=, 2 = store fp32
template <int EPI>
__global__ __launch_bounds__(256, 2) void k_gemm(const unsigned short* __restrict__ A,
    const unsigned short* __restrict__ BT, void* __restrict__ Cout,
    int N, int K, int nbm) {
  __shared__ unsigned short As[128 * 64];
  __shared__ unsigned short Bs[128 * 64];
  // bijective XCD swizzle: contiguous wgid chunk per XCD
  const int nwg = gridDim.x;
  const int orig = blockIdx.x;
  const int q8 = nwg >> 3, r8 = nwg & 7;
  const int xcd = orig & 7, i8 = orig >> 3;
  const int wgid = (xcd < r8 ? xcd * (q8 + 1) : r8 * (q8 + 1) + (xcd - r8) * q8) + i8;
  const int bm = wgid % nbm;  // bm-fast: consecutive blocks share the B panel
  const int bn = wgid / nbm;
  const int t = threadIdx.x;
  const int w = t >> 6, l = t & 63;
  const int wm = w >> 1, wn = w & 1;   // 2x2 waves, 64x64 each
  const int lrow = l >> 3, lch = l & 7;
  const int lq = l & 15, lk = l >> 4;
  f32x4 acc[4][4] = {};
  const long arow0 = (long)bm * 128, brow0 = (long)bn * 128;
  for (int kt = 0; kt < K; kt += 64) {
    __syncthreads();
#pragma unroll
    for (int s2 = 0; s2 < 4; ++s2) {
      int grp = s2 * 4 + w;
      int r = grp * 8 + lrow;
      int gch = lch ^ lrow;
      gload_lds16(A + (arow0 + r) * K + kt + gch * 8, &As[grp * 512]);
      gload_lds16(BT + (brow0 + r) * K + kt + gch * 8, &Bs[grp * 512]);
    }
    asm volatile("s_waitcnt vmcnt(0)" ::: "memory");
    __syncthreads();
#pragma unroll
    for (int kk = 0; kk < 2; ++kk) {
      bf16x8 af[4], bfr[4];
#pragma unroll
      for (int i = 0; i < 4; ++i) {
        int ra = wm * 64 + i * 16 + lq;
        af[i] = *(const bf16x8*)&As[ra * 64 + (((kk * 4 + lk) ^ (ra & 7)) * 8)];
        int rb = wn * 64 + i * 16 + lq;
        bfr[i] = *(const bf16x8*)&Bs[rb * 64 + (((kk * 4 + lk) ^ (rb & 7)) * 8)];
      }
#pragma unroll
      for (int i = 0; i < 4; ++i)
#pragma unroll
        for (int j = 0; j < 4; ++j)
          acc[i][j] = __builtin_amdgcn_mfma_f32_16x16x32_bf16(af[i], bfr[j],
                                                              acc[i][j], 0, 0, 0);
    }
  }
  const int rbase = bm * 128 + wm * 64 + lk * 4;
  const int cbase = bn * 128 + wn * 64 + lq;
#pragma unroll
  for (int i = 0; i < 4; ++i) {
#pragma unroll
    for (int j = 0; j < 4; ++j) {
#pragma unroll
      for (int r2 = 0; r2 < 4; ++r2) {
        long row = rbase + i * 16 + r2;
        long col = cbase + j * 16;
        float v = acc[i][j][r2];
        if (EPI == 0)
          ((unsigned short*)Cout)[row * N + col] = f2bf(v);
        else if (EPI == 1)
          ((float*)Cout)[row * N + col] += v;
        else
          ((float*)Cout)[row * N + col] = v;
      }
    }
  }
}

extern "C" void kernel_launch(void* const* d_in, const int* in_sizes, int n_in,
                              void* d_out, int out_size, void* d_ws, size_t ws_size,
                              hipStream_t stream) {
  (void)in_sizes; (void)n_in; (void)out_size; (void)ws_size;
  const int* tokens   = (const int*)d_in[0];
  const float* tok_emb = (const float*)d_in[1];
  const float* pos_emb = (const float*)d_in[2];
  const float* dpb_w1 = (const float*)d_in[3];
  const float* dpb_b1 = (const float*)d_in[4];
  const float* dpb_w2 = (const float*)d_in[5];
  const float* dpb_b2 = (const float*)d_in[6];
  const float* dpb_w3 = (const float*)d_in[7];
  const float* dpb_b3 = (const float*)d_in[8];
  const float* ln1_g  = (const float*)d_in[9];
  const float* ln1_b  = (const float*)d_in[10];
  const float* Wqkv   = (const float*)d_in[11];
  const float* Wo     = (const float*)d_in[12];
  const float* ln2_g  = (const float*)d_in[13];
  const float* ln2_b  = (const float*)d_in[14];
  const float* Wff1   = (const float*)d_in[15];
  const float* Wff2   = (const float*)d_in[16];
  const float* lnf_g  = (const float*)d_in[17];
  const float* lnf_b  = (const float*)d_in[18];
  const float* Wlog   = (const float*)d_in[19];
  float* out = (float*)d_out;

  char* p = (char*)d_ws;
  auto carve = [&](size_t bytes) {
    char* q = p;
    p += (bytes + 255) & ~(size_t)255;
    return (void*)q;
  };
  unsigned short* WqkvT = (unsigned short*)carve((size_t)4 * 3072 * 1024 * 2);
  unsigned short* WoT   = (unsigned short*)carve((size_t)4 * 1024 * 1024 * 2);
  unsigned short* Wff1T = (unsigned short*)carve((size_t)4 * 5504 * 1024 * 2);
  unsigned short* Wff2T = (unsigned short*)carve((size_t)4 * 1024 * 2752 * 2);
  unsigned short* WlogT = (unsigned short*)carve((size_t)32000 * 1024 * 2);
  float*          x     = (float*)carve((size_t)2048 * 1024 * 4);
  unsigned short* hbuf  = (unsigned short*)carve((size_t)2048 * 1024 * 2);
  unsigned short* qkv   = (unsigned short*)carve((size_t)2048 * 3072 * 2);
  unsigned short* ao    = (unsigned short*)carve((size_t)2048 * 1024 * 2);
  unsigned short* ff    = (unsigned short*)carve((size_t)2048 * 5504 * 2);
  unsigned short* ubuf  = (unsigned short*)carve((size_t)2048 * 2752 * 2);
  float*          table = (float*)carve((size_t)1024 * 16 * 4);

  k_wconv<<<dim3(3072 / 32, 1024 / 32, 4), 256, 0, stream>>>(
      Wqkv, WqkvT, 1024, 3072, 1024, 3072, (long)1024 * 3072, (long)3072 * 1024);
  k_wconv<<<dim3(1024 / 32, 1024 / 32, 4), 256, 0, stream>>>(
      Wo, WoT, 1024, 1024, 1024, 1024, (long)1024 * 1024, (long)1024 * 1024);
  k_wconv<<<dim3(5504 / 32, 1024 / 32, 4), 256, 0, stream>>>(
      Wff1, Wff1T, 1024, 5460, 1024, 5504, (long)1024 * 5460, (long)5504 * 1024);
  k_wconv<<<dim3(1024 / 32, 2752 / 32, 4), 256, 0, stream>>>(
      Wff2, Wff2T, 2730, 1024, 2752, 1024, (long)2730 * 1024, (long)1024 * 2752);
  k_wconv<<<dim3(32000 / 32, 1024 / 32, 1), 256, 0, stream>>>(
      Wlog, WlogT, 1024, 32000, 1024, 32000, 0L, 0L);

  k_dpb<<<1024, 256, 0, stream>>>(dpb_w1, dpb_b1, dpb_w2, dpb_b2, dpb_w3, dpb_b3, table);
  k_embed<<<2048, 256, 0, stream>>>(tokens, tok_emb, pos_emb, x);

  const int NBM = 16;  // 2048 / 128
  for (int l = 0; l < 4; ++l) {
    k_ln<<<2048, 256, 0, stream>>>(x, ln1_g + l * 1024, ln1_b + l * 1024, hbuf);
    k_gemm<0><<<dim3(NBM * (3072 / 128)), 256, 0, stream>>>(
        hbuf, WqkvT + (long)l * 3072 * 1024, qkv, 3072, 1024, NBM);
    k_attn_mfma<<<dim3(8, 16, 4), 256, 0, stream>>>(qkv, table, ao);
    k_gemm<1><<<dim3(NBM * (1024 / 128)), 256, 0, stream>>>(
        ao, WoT + (long)l * 1024 * 1024, x, 1024, 1024, NBM);
    k_ln<<<2048, 256, 0, stream>>>(x, ln2_g + l * 1024, ln2_b + l * 1024, hbuf);
    k_gemm<0><<<dim3(NBM * (5504 / 128)), 256, 0, stream>>>(
        hbuf, Wff1T + (long)l * 5504 * 1024, ff, 5504, 1024, NBM);
    k_glu<<<2048, 256, 0, stream>>>(ff, ubuf);
    k_gemm<1><<<dim3(NBM * (1024 / 128)), 256, 0, stream>>>(
        ubuf, Wff2T + (long)l * 1024 * 2752, x, 1024, 2752, NBM);
  }
  k_ln<<<2048, 256, 0, stream>>>(x, lnf_g, lnf_b, hbuf);
  k_gemm<2><<<dim3(NBM * (32000 / 128)), 256, 0, stream>>>(
      hbuf, WlogT, out, 32000, 1024, NBM);
}

// Round 4
// 1148.233 us; speedup vs baseline: 2.7198x; 1.0298x over previous
//
#include <hip/hip_runtime.h>
#include <cstdint>

#define DEV __device__ __forceinline__

typedef __attribute__((ext_vector_type(8))) short bf16x8;
typedef __attribute__((ext_vector_type(4))) short bf16x4;
typedef __attribute__((ext_vector_type(4))) float f32x4;

DEV float bf2f(unsigned short u) { return __uint_as_float(((unsigned)u) << 16); }
DEV unsigned short f2bf(float f) {
  unsigned u = __float_as_uint(f);
  u += 0x7FFFu + ((u >> 16) & 1u);
  return (unsigned short)(u >> 16);
}

DEV void gload_lds16(const void* g, void* lds) {
  __builtin_amdgcn_global_load_lds(
      (const __attribute__((address_space(1))) unsigned int*)g,
      (__attribute__((address_space(3))) unsigned int*)lds, 16, 0, 0);
}

// ---------------- prep mega-kernel: embed + dpb + all weight conversions ----
// block ranges: [0,2048) embed | [2048,3072) dpb | rest: wconv sections
__global__ __launch_bounds__(256) void k_prep(
    const int* __restrict__ tokens, const float* __restrict__ tok_emb,
    const float* __restrict__ pos_emb, float* __restrict__ x,
    const float* __restrict__ w1, const float* __restrict__ b1,
    const float* __restrict__ w2, const float* __restrict__ b2,
    const float* __restrict__ w3, const float* __restrict__ b3,
    float* __restrict__ table,
    const float* __restrict__ Wqkv, unsigned short* __restrict__ WqkvT,
    const float* __restrict__ Wo, unsigned short* __restrict__ WoT,
    const float* __restrict__ Wff1, unsigned short* __restrict__ Wff1T,
    const float* __restrict__ Wff2, unsigned short* __restrict__ Wff2T,
    const float* __restrict__ Wlog, unsigned short* __restrict__ WlogT) {
  __shared__ float smem[1056];
  int b = blockIdx.x, t = threadIdx.x;
  if (b < 2048) {  // ---- embed ----
    int tok = tokens[b];
    int c = t * 4;
    float4 a = *(const float4*)(tok_emb + (long)tok * 1024 + c);
    float4 p = *(const float4*)(pos_emb + (long)b * 1024 + c);
    float4 r;
    r.x = a.x + p.x; r.y = a.y + p.y; r.z = a.z + p.z; r.w = a.w + p.w;
    *(float4*)(x + (long)b * 1024 + c) = r;
    return;
  }
  b -= 2048;
  if (b < 1024) {  // ---- dpb: one rel-position per block ----
    float* h1 = smem;
    float* h2 = smem + 512;
    float rf = (float)b;
    for (int c = t; c < 512; c += 256) {
      float v = rf * w1[c] + b1[c];
      h1[c] = v / (1.0f + __expf(-v));
    }
    __syncthreads();
    for (int c = t; c < 512; c += 256) {
      float acc = b2[c];
      for (int k2 = 0; k2 < 512; ++k2) acc = fmaf(h1[k2], w2[(long)k2 * 512 + c], acc);
      h2[c] = acc / (1.0f + __expf(-acc));
    }
    __syncthreads();
    if (t < 16) {
      float acc = b3[t];
      for (int k2 = 0; k2 < 512; ++k2) acc = fmaf(h2[k2], w3[k2 * 16 + t], acc);
      table[b * 16 + t] = acc;
    }
    return;
  }
  b -= 1024;
  // ---- wconv: fp32 (K,N) -> bf16 W^T (Np rows, Kp cols), zero-padded ----
  const float* src; unsigned short* dst;
  int K, N, Kp, nx, ny, mode;
  long ss, ds;
  if (b < 12288) {
    src = Wqkv; dst = WqkvT; K = 1024; N = 3072; Kp = 1024;
    nx = 96; ny = 32; mode = 0; ss = 1024L * 3072; ds = 3072L * 1024;
  } else if ((b -= 12288) < 4096) {
    src = Wo; dst = WoT; K = 1024; N = 1024; Kp = 1024;
    nx = 32; ny = 32; mode = 0; ss = 1024L * 1024; ds = 1024L * 1024;
  } else if ((b -= 4096) < 22016) {
    src = Wff1; dst = Wff1T; K = 1024; N = 5460; Kp = 1024;
    nx = 172; ny = 32; mode = 1; ss = 1024L * 5460; ds = 5504L * 1024;
  } else if ((b -= 22016) < 11008) {
    src = Wff2; dst = Wff2T; K = 2730; N = 1024; Kp = 2752;
    nx = 32; ny = 86; mode = 0; ss = 2730L * 1024; ds = 1024L * 2752;
  } else {
    b -= 11008;
    src = Wlog; dst = WlogT; K = 1024; N = 32000; Kp = 1024;
    nx = 1000; ny = 32; mode = 0; ss = 0; ds = 0;
  }
  int z = b / (nx * ny);
  int rem = b % (nx * ny);
  int n0 = (rem % nx) * 32, k0 = (rem / nx) * 32;
  src += (long)z * ss;
  dst += (long)z * ds;
  float (*tile)[33] = (float(*)[33])smem;
  int r = t >> 3, c4 = (t & 7) * 4;
  int k = k0 + r, n = n0 + c4;
  float4 v = make_float4(0.f, 0.f, 0.f, 0.f);
  if (k < K && n < N) v = *(const float4*)(src + (long)k * N + n);  // all N % 4 == 0
  tile[r][c4 + 0] = v.x;
  tile[r][c4 + 1] = v.y;
  tile[r][c4 + 2] = v.z;
  tile[r][c4 + 3] = v.w;
  __syncthreads();
  int nrow = n0 + r;
  // mode 1: interleave a/gate features -> rows (2f, 2f+1) for fused GLU epilogue
  if (mode) nrow = nrow < 2730 ? 2 * nrow : (nrow < 5460 ? 2 * (nrow - 2730) + 1 : nrow);
  ushort4 o;
  o.x = f2bf(tile[c4 + 0][r]);
  o.y = f2bf(tile[c4 + 1][r]);
  o.z = f2bf(tile[c4 + 2][r]);
  o.w = f2bf(tile[c4 + 3][r]);
  *(ushort4*)(dst + (long)nrow * Kp + k0 + c4) = o;
}

// ---------------- layernorm: one wave per row, 4 rows/block ----------------
__global__ __launch_bounds__(256) void k_ln4(const float* __restrict__ x,
    const float* __restrict__ g, const float* __restrict__ b,
    unsigned short* __restrict__ out) {
  const int row = blockIdx.x * 4 + (threadIdx.x >> 6);
  const int l = threadIdx.x & 63;
  const float* xr = x + (long)row * 1024 + l * 16;
  float4 v[4];
#pragma unroll
  for (int e = 0; e < 4; ++e) v[e] = ((const float4*)xr)[e];
  float s = 0.0f;
#pragma unroll
  for (int e = 0; e < 4; ++e) s += v[e].x + v[e].y + v[e].z + v[e].w;
#pragma unroll
  for (int off = 32; off; off >>= 1) s += __shfl_xor(s, off);
  float mean = s * (1.0f / 1024.0f);
  float sq = 0.0f;
#pragma unroll
  for (int e = 0; e < 4; ++e) {
    float a0 = v[e].x - mean, a1 = v[e].y - mean, a2 = v[e].z - mean, a3 = v[e].w - mean;
    sq += a0 * a0 + a1 * a1 + a2 * a2 + a3 * a3;
  }
#pragma unroll
  for (int off = 32; off; off >>= 1) sq += __shfl_xor(sq, off);
  float inv = rsqrtf(sq * (1.0f / 1024.0f) + 1e-5f);
  const float* gr = g + l * 16;
  const float* br = b + l * 16;
  unsigned short* orow = out + (long)row * 1024 + l * 16;
#pragma unroll
  for (int e = 0; e < 4; ++e) {
    float4 gv = ((const float4*)gr)[e];
    float4 bv = ((const float4*)br)[e];
    ushort4 o;
    o.x = f2bf((v[e].x - mean) * inv * gv.x + bv.x);
    o.y = f2bf((v[e].y - mean) * inv * gv.y + bv.y);
    o.z = f2bf((v[e].z - mean) * inv * gv.z + bv.z);
    o.w = f2bf((v[e].w - mean) * inv * gv.w + bv.w);
    ((ushort4*)orow)[e] = o;
  }
}

// ---------------- MFMA flash local attention ----------------
__global__ __launch_bounds__(256, 2) void k_attn_mfma(
    const unsigned short* __restrict__ qkv, const float* __restrict__ table,
    unsigned short* __restrict__ o) {
  __shared__ unsigned short Ks[64 * 64];      // swizzled rows (key), 8 chunks of 8
  __shared__ unsigned short Vt[64 * 72];      // Vt[d][key], stride 72
  __shared__ unsigned short Ps[4][16 * 72];   // per-wave P, stride 72
  __shared__ float biasl[1024];
  const int qt = blockIdx.x, h = blockIdx.y, wi = blockIdx.z;
  const int iw0 = qt * 64;
  const int t = threadIdx.x;
  const int w = t >> 6, l = t & 63;
  const int lq = l & 15, lk = l >> 4;

  for (int i = t; i < 1024; i += 256) biasl[i] = table[i * 16 + h];

  const unsigned short* qp = qkv + (long)(wi * 512 + iw0 + w * 16 + lq) * 3072 + h * 64;
  bf16x8 qf0 = *(const bf16x8*)(qp + lk * 8);
  bf16x8 qf1 = *(const bf16x8*)(qp + 32 + lk * 8);

  f32x4 oacc[4] = {};
  float mrun[4] = {-3.0e38f, -3.0e38f, -3.0e38f, -3.0e38f};
  float srun[4] = {};

  const int kt0 = (wi == 0) ? 8 : qt;
  const int kt1 = qt + 8;
  for (int kt = kt0; kt <= kt1; ++kt) {
    const int ktbase = kt * 64;
    const long kgbase = (long)((wi - 1) * 512 + ktbase);
    __syncthreads();
    {
      const unsigned short* Kg = qkv + kgbase * 3072 + 1024 + h * 64;
#pragma unroll
      for (int s2 = 0; s2 < 2; ++s2) {
        int g = s2 * 4 + w;
        int row = g * 8 + (l >> 3);
        int gch = (l & 7) ^ (row & 7);
        gload_lds16(Kg + (long)row * 3072 + gch * 8, &Ks[g * 512]);
      }
    }
    {
      int kp = t & 31, dg = t >> 5;
      const unsigned short* Vg =
          qkv + (kgbase + 2 * kp) * 3072 + 2048 + h * 64 + dg * 8;
      bf16x8 a0 = *(const bf16x8*)Vg;
      bf16x8 a1 = *(const bf16x8*)(Vg + 3072);
#pragma unroll
      for (int e = 0; e < 8; ++e) {
        unsigned pack = ((unsigned)(unsigned short)a0[e]) |
                        (((unsigned)(unsigned short)a1[e]) << 16);
        *(unsigned*)&Vt[(dg * 8 + e) * 72 + 2 * kp] = pack;
      }
    }
    asm volatile("s_waitcnt vmcnt(0)" ::: "memory");
    __syncthreads();

    f32x4 sacc[4] = {};
#pragma unroll
    for (int ct = 0; ct < 4; ++ct) {
      int krow = ct * 16 + lq;
      bf16x8 kf0 = *(const bf16x8*)&Ks[krow * 64 + (((0 + lk) ^ (krow & 7)) * 8)];
      bf16x8 kf1 = *(const bf16x8*)&Ks[krow * 64 + (((4 + lk) ^ (krow & 7)) * 8)];
      sacc[ct] = __builtin_amdgcn_mfma_f32_16x16x32_bf16(qf0, kf0, sacc[ct], 0, 0, 0);
      sacc[ct] = __builtin_amdgcn_mfma_f32_16x16x32_bf16(qf1, kf1, sacc[ct], 0, 0, 0);
    }

#pragma unroll
    for (int r = 0; r < 4; ++r) {
      const int iw = iw0 + w * 16 + lk * 4 + r;
      float sc[4];
#pragma unroll
      for (int ct = 0; ct < 4; ++ct) {
        int jj = ktbase + ct * 16 + lq;
        int di = 512 + iw - jj;
        int dic = min(max(di, 0), 1023);
        bool allowed = (jj >= iw) && (jj <= iw + 512);
        float v = sacc[ct][r] * 0.125f + biasl[dic];
        sc[ct] = allowed ? v : -3.0e38f;
      }
      float mx = fmaxf(fmaxf(sc[0], sc[1]), fmaxf(sc[2], sc[3]));
      mx = fmaxf(mx, __shfl_xor(mx, 1));
      mx = fmaxf(mx, __shfl_xor(mx, 2));
      mx = fmaxf(mx, __shfl_xor(mx, 4));
      mx = fmaxf(mx, __shfl_xor(mx, 8));
      float mnew = fmaxf(mrun[r], mx);
      float f = __expf(mrun[r] - mnew);
      mrun[r] = mnew;
      float rs = 0.0f;
#pragma unroll
      for (int ct = 0; ct < 4; ++ct) {
        float pv = __expf(sc[ct] - mnew);
        rs += pv;
        Ps[w][(lk * 4 + r) * 72 + ct * 16 + lq] = f2bf(pv);
      }
      rs += __shfl_xor(rs, 1);
      rs += __shfl_xor(rs, 2);
      rs += __shfl_xor(rs, 4);
      rs += __shfl_xor(rs, 8);
      srun[r] = srun[r] * f + rs;
#pragma unroll
      for (int dt = 0; dt < 4; ++dt) oacc[dt][r] *= f;
    }
    asm volatile("s_waitcnt lgkmcnt(0)" ::: "memory");

#pragma unroll
    for (int ks = 0; ks < 2; ++ks) {
      bf16x4 pa0 = *(const bf16x4*)&Ps[w][lq * 72 + ks * 32 + lk * 8];
      bf16x4 pa1 = *(const bf16x4*)&Ps[w][lq * 72 + ks * 32 + lk * 8 + 4];
      bf16x8 pa = __builtin_shufflevector(pa0, pa1, 0, 1, 2, 3, 4, 5, 6, 7);
#pragma unroll
      for (int dt = 0; dt < 4; ++dt) {
        int drow = dt * 16 + lq;
        bf16x4 vb0 = *(const bf16x4*)&Vt[drow * 72 + ks * 32 + lk * 8];
        bf16x4 vb1 = *(const bf16x4*)&Vt[drow * 72 + ks * 32 + lk * 8 + 4];
        bf16x8 vb = __builtin_shufflevector(vb0, vb1, 0, 1, 2, 3, 4, 5, 6, 7);
        oacc[dt] = __builtin_amdgcn_mfma_f32_16x16x32_bf16(pa, vb, oacc[dt], 0, 0, 0);
      }
    }
  }

  unsigned short* ob =
      o + (long)(wi * 512 + iw0 + w * 16 + lk * 4) * 1024 + h * 64 + lq;
#pragma unroll
  for (int r = 0; r < 4; ++r) {
    float inv = 1.0f / srun[r];
#pragma unroll
    for (int dt = 0; dt < 4; ++dt)
      ob[(long)r * 1024 + dt * 16] = f2bf(oacc[dt][r] * inv);
  }
}

// ---------------- GEMM: C(M,N) = A(M,K) * B^T(N,K), bf16 MFMA ----------------
// 1D grid, bm-fast ordering + bijective XCD swizzle for B-panel L2 reuse.
// EPI: 0 = store bf16, 1 = fp32 +=, 2 = store fp32,
//      3 = fused GLU (interleaved a/gate cols) -> bf16 u at stride N/2
template <int EPI>
__global__ __launch_bounds__(256, 2) void k_gemm(const unsigned short* __restrict__ A,
    const unsigned short* __restrict__ BT, void* __restrict__ Cout,
    int N, int K, int nbm) {
  __shared__ unsigned short As[128 * 64];
  __shared__ unsigned short Bs[128 * 64];
  const int nwg = gridDim.x;
  const int orig = blockIdx.x;
  const int q8 = nwg >> 3, r8 = nwg & 7;
  const int xcd = orig & 7, i8 = orig >> 3;
  const int wgid = (xcd < r8 ? xcd * (q8 + 1) : r8 * (q8 + 1) + (xcd - r8) * q8) + i8;
  const int bm = wgid % nbm;  // bm-fast: consecutive blocks share the B panel
  const int bn = wgid / nbm;
  const int t = threadIdx.x;
  const int w = t >> 6, l = t & 63;
  const int wm = w >> 1, wn = w & 1;   // 2x2 waves, 64x64 each
  const int lrow = l >> 3, lch = l & 7;
  const int lq = l & 15, lk = l >> 4;
  f32x4 acc[4][4] = {};
  const long arow0 = (long)bm * 128, brow0 = (long)bn * 128;
  for (int kt = 0; kt < K; kt += 64) {
    __syncthreads();
#pragma unroll
    for (int s2 = 0; s2 < 4; ++s2) {
      int grp = s2 * 4 + w;
      int r = grp * 8 + lrow;
      int gch = lch ^ lrow;
      gload_lds16(A + (arow0 + r) * K + kt + gch * 8, &As[grp * 512]);
      gload_lds16(BT + (brow0 + r) * K + kt + gch * 8, &Bs[grp * 512]);
    }
    asm volatile("s_waitcnt vmcnt(0)" ::: "memory");
    __syncthreads();
#pragma unroll
    for (int kk = 0; kk < 2; ++kk) {
      bf16x8 af[4], bfr[4];
#pragma unroll
      for (int i = 0; i < 4; ++i) {
        int ra = wm * 64 + i * 16 + lq;
        af[i] = *(const bf16x8*)&As[ra * 64 + (((kk * 4 + lk) ^ (ra & 7)) * 8)];
        int rb = wn * 64 + i * 16 + lq;
        bfr[i] = *(const bf16x8*)&Bs[rb * 64 + (((kk * 4 + lk) ^ (rb & 7)) * 8)];
      }
#pragma unroll
      for (int i = 0; i < 4; ++i)
#pragma unroll
        for (int j = 0; j < 4; ++j)
          acc[i][j] = __builtin_amdgcn_mfma_f32_16x16x32_bf16(af[i], bfr[j],
                                                              acc[i][j], 0, 0, 0);
    }
  }
  const int rbase = bm * 128 + wm * 64 + lk * 4;
  const int cbase = bn * 128 + wn * 64 + lq;
#pragma unroll
  for (int i = 0; i < 4; ++i) {
#pragma unroll
    for (int j = 0; j < 4; ++j) {
#pragma unroll
      for (int r2 = 0; r2 < 4; ++r2) {
        long row = rbase + i * 16 + r2;
        long col = cbase + j * 16;
        float v = acc[i][j][r2];
        if (EPI == 0) {
          ((unsigned short*)Cout)[row * N + col] = f2bf(v);
        } else if (EPI == 1) {
          ((float*)Cout)[row * N + col] += v;
        } else if (EPI == 2) {
          ((float*)Cout)[row * N + col] = v;
        } else {
          // fused GLU: even col = a, odd col = gate (same feature f = col>>1)
          float gpart = __shfl_xor(v, 1);
          if ((lq & 1) == 0) {
            float uval =
                v * (0.5f * gpart * (1.0f + erff(gpart * 0.70710678118654752f)));
            ((unsigned short*)Cout)[row * (N >> 1) + (col >> 1)] = f2bf(uval);
          }
        }
      }
    }
  }
}

extern "C" void kernel_launch(void* const* d_in, const int* in_sizes, int n_in,
                              void* d_out, int out_size, void* d_ws, size_t ws_size,
                              hipStream_t stream) {
  (void)in_sizes; (void)n_in; (void)out_size; (void)ws_size;
  const int* tokens   = (const int*)d_in[0];
  const float* tok_emb = (const float*)d_in[1];
  const float* pos_emb = (const float*)d_in[2];
  const float* dpb_w1 = (const float*)d_in[3];
  const float* dpb_b1 = (const float*)d_in[4];
  const float* dpb_w2 = (const float*)d_in[5];
  const float* dpb_b2 = (const float*)d_in[6];
  const float* dpb_w3 = (const float*)d_in[7];
  const float* dpb_b3 = (const float*)d_in[8];
  const float* ln1_g  = (const float*)d_in[9];
  const float* ln1_b  = (const float*)d_in[10];
  const float* Wqkv   = (const float*)d_in[11];
  const float* Wo     = (const float*)d_in[12];
  const float* ln2_g  = (const float*)d_in[13];
  const float* ln2_b  = (const float*)d_in[14];
  const float* Wff1   = (const float*)d_in[15];
  const float* Wff2   = (const float*)d_in[16];
  const float* lnf_g  = (const float*)d_in[17];
  const float* lnf_b  = (const float*)d_in[18];
  const float* Wlog   = (const float*)d_in[19];
  float* out = (float*)d_out;

  char* p = (char*)d_ws;
  auto carve = [&](size_t bytes) {
    char* q = p;
    p += (bytes + 255) & ~(size_t)255;
    return (void*)q;
  };
  unsigned short* WqkvT = (unsigned short*)carve((size_t)4 * 3072 * 1024 * 2);
  unsigned short* WoT   = (unsigned short*)carve((size_t)4 * 1024 * 1024 * 2);
  unsigned short* Wff1T = (unsigned short*)carve((size_t)4 * 5504 * 1024 * 2);
  unsigned short* Wff2T = (unsigned short*)carve((size_t)4 * 1024 * 2752 * 2);
  unsigned short* WlogT = (unsigned short*)carve((size_t)32000 * 1024 * 2);
  float*          x     = (float*)carve((size_t)2048 * 1024 * 4);
  unsigned short* hbuf  = (unsigned short*)carve((size_t)2048 * 1024 * 2);
  unsigned short* qkv   = (unsigned short*)carve((size_t)2048 * 3072 * 2);
  unsigned short* ao    = (unsigned short*)carve((size_t)2048 * 1024 * 2);
  unsigned short* ubuf  = (unsigned short*)carve((size_t)2048 * 2752 * 2);
  float*          table = (float*)carve((size_t)1024 * 16 * 4);

  // prep: embed(2048) + dpb(1024) + wconv(81408) = 84480 blocks, one launch
  k_prep<<<84480, 256, 0, stream>>>(
      tokens, tok_emb, pos_emb, x, dpb_w1, dpb_b1, dpb_w2, dpb_b2, dpb_w3,
      dpb_b3, table, Wqkv, WqkvT, Wo, WoT, Wff1, Wff1T, Wff2, Wff2T, Wlog, WlogT);

  const int NBM = 16;  // 2048 / 128
  for (int l = 0; l < 4; ++l) {
    k_ln4<<<512, 256, 0, stream>>>(x, ln1_g + l * 1024, ln1_b + l * 1024, hbuf);
    k_gemm<0><<<dim3(NBM * (3072 / 128)), 256, 0, stream>>>(
        hbuf, WqkvT + (long)l * 3072 * 1024, qkv, 3072, 1024, NBM);
    k_attn_mfma<<<dim3(8, 16, 4), 256, 0, stream>>>(qkv, table, ao);
    k_gemm<1><<<dim3(NBM * (1024 / 128)), 256, 0, stream>>>(
        ao, WoT + (long)l * 1024 * 1024, x, 1024, 1024, NBM);
    k_ln4<<<512, 256, 0, stream>>>(x, ln2_g + l * 1024, ln2_b + l * 1024, hbuf);
    k_gemm<3><<<dim3(NBM * (5504 / 128)), 256, 0, stream>>>(
        hbuf, Wff1T + (long)l * 5504 * 1024, ubuf, 5504, 1024, NBM);
    k_gemm<1><<<dim3(NBM * (1024 / 128)), 256, 0, stream>>>(
        ubuf, Wff2T + (long)l * 1024 * 2752, x, 1024, 2752, NBM);
  }
  k_ln4<<<512, 256, 0, stream>>>(x, lnf_g, lnf_b, hbuf);
  k_gemm<2><<<dim3(NBM * (32000 / 128)), 256, 0, stream>>>(
      hbuf, WlogT, out, 32000, 1024, NBM);
}

// Round 5
// 1046.557 us; speedup vs baseline: 2.9840x; 1.0972x over previous
//
#include <hip/hip_runtime.h>
#include <cstdint>

#define DEV __device__ __forceinline__

typedef __attribute__((ext_vector_type(8))) short bf16x8;
typedef __attribute__((ext_vector_type(4))) short bf16x4;
typedef __attribute__((ext_vector_type(4))) float f32x4;
typedef __attribute__((ext_vector_type(8))) unsigned short u16x8;

DEV float bf2f(unsigned short u) { return __uint_as_float(((unsigned)u) << 16); }
DEV unsigned short f2bf(float f) {
  unsigned u = __float_as_uint(f);
  u += 0x7FFFu + ((u >> 16) & 1u);
  return (unsigned short)(u >> 16);
}

DEV void gload_lds16(const void* g, void* lds) {
  __builtin_amdgcn_global_load_lds(
      (const __attribute__((address_space(1))) unsigned int*)g,
      (__attribute__((address_space(3))) unsigned int*)lds, 16, 0, 0);
}

// ---------------- prep mega-kernel: embed + dpb + all weight conversions ----
// block ranges: [0,2048) embed | [2048,3072) dpb | rest: wconv 64x64 tiles
__global__ __launch_bounds__(256) void k_prep(
    const int* __restrict__ tokens, const float* __restrict__ tok_emb,
    const float* __restrict__ pos_emb, float* __restrict__ x,
    const float* __restrict__ w1, const float* __restrict__ b1,
    const float* __restrict__ w2, const float* __restrict__ b2,
    const float* __restrict__ w3, const float* __restrict__ b3,
    float* __restrict__ table,
    const float* __restrict__ Wqkv, unsigned short* __restrict__ WqkvT,
    const float* __restrict__ Wo, unsigned short* __restrict__ WoT,
    const float* __restrict__ Wff1, unsigned short* __restrict__ Wff1T,
    const float* __restrict__ Wff2, unsigned short* __restrict__ Wff2T,
    const float* __restrict__ Wlog, unsigned short* __restrict__ WlogT) {
  __shared__ float smem[64 * 65];
  int b = blockIdx.x, t = threadIdx.x;
  if (b < 2048) {  // ---- embed ----
    int tok = tokens[b];
    int c = t * 4;
    float4 a = *(const float4*)(tok_emb + (long)tok * 1024 + c);
    float4 p = *(const float4*)(pos_emb + (long)b * 1024 + c);
    float4 r;
    r.x = a.x + p.x; r.y = a.y + p.y; r.z = a.z + p.z; r.w = a.w + p.w;
    *(float4*)(x + (long)b * 1024 + c) = r;
    return;
  }
  b -= 2048;
  if (b < 1024) {  // ---- dpb: one rel-position per block ----
    float* h1 = smem;
    float* h2 = smem + 512;
    float rf = (float)b;
    for (int c = t; c < 512; c += 256) {
      float v = rf * w1[c] + b1[c];
      h1[c] = v / (1.0f + __expf(-v));
    }
    __syncthreads();
    for (int c = t; c < 512; c += 256) {
      float acc = b2[c];
      for (int k2 = 0; k2 < 512; ++k2) acc = fmaf(h1[k2], w2[(long)k2 * 512 + c], acc);
      h2[c] = acc / (1.0f + __expf(-acc));
    }
    __syncthreads();
    if (t < 16) {
      float acc = b3[t];
      for (int k2 = 0; k2 < 512; ++k2) acc = fmaf(h2[k2], w3[k2 * 16 + t], acc);
      table[b * 16 + t] = acc;
    }
    return;
  }
  b -= 1024;
  // ---- wconv: fp32 (K,N) -> bf16 W^T (Np rows, Kp cols), 64x64 tiles ----
  const float* src; unsigned short* dst;
  int K, N, Kp, nx, ny, mode;
  long ss, ds;
  if (b < 3072) {
    src = Wqkv; dst = WqkvT; K = 1024; N = 3072; Kp = 1024;
    nx = 48; ny = 16; mode = 0; ss = 1024L * 3072; ds = 3072L * 1024;
  } else if ((b -= 3072) < 1024) {
    src = Wo; dst = WoT; K = 1024; N = 1024; Kp = 1024;
    nx = 16; ny = 16; mode = 0; ss = 1024L * 1024; ds = 1024L * 1024;
  } else if ((b -= 1024) < 5504) {
    src = Wff1; dst = Wff1T; K = 1024; N = 5460; Kp = 1024;
    nx = 86; ny = 16; mode = 1; ss = 1024L * 5460; ds = 5504L * 1024;
  } else if ((b -= 5504) < 2752) {
    src = Wff2; dst = Wff2T; K = 2730; N = 1024; Kp = 2752;
    nx = 16; ny = 43; mode = 0; ss = 2730L * 1024; ds = 1024L * 2752;
  } else {
    b -= 2752;
    src = Wlog; dst = WlogT; K = 1024; N = 32000; Kp = 1024;
    nx = 500; ny = 16; mode = 0; ss = 0; ds = 0;
  }
  int z = b / (nx * ny);
  int rem = b % (nx * ny);
  int n0 = (rem % nx) * 64, k0 = (rem / nx) * 64;
  src += (long)z * ss;
  dst += (long)z * ds;
  float (*tile)[65] = (float(*)[65])smem;
  const int cr = t >> 4, cc = (t & 15) * 4;
#pragma unroll
  for (int i = 0; i < 4; ++i) {
    int kr = cr + 16 * i;
    int k = k0 + kr, n = n0 + cc;
    float4 v = make_float4(0.f, 0.f, 0.f, 0.f);
    if (k < K && n < N) v = *(const float4*)(src + (long)k * N + n);  // N%4==0
    tile[kr][cc + 0] = v.x;
    tile[kr][cc + 1] = v.y;
    tile[kr][cc + 2] = v.z;
    tile[kr][cc + 3] = v.w;
  }
  __syncthreads();
  const int kc = (t & 7) * 8;
#pragma unroll
  for (int it = 0; it < 2; ++it) {
    int nr = (t >> 3) + 32 * it;
    u16x8 o;
#pragma unroll
    for (int e = 0; e < 8; ++e) o[e] = f2bf(tile[kc + e][nr]);
    int nrow = n0 + nr;
    // mode 1: interleave a/gate features -> rows (2f, 2f+1) for fused GLU
    if (mode)
      nrow = nrow < 2730 ? 2 * nrow : (nrow < 5460 ? 2 * (nrow - 2730) + 1 : nrow);
    *(u16x8*)(dst + (long)nrow * Kp + k0 + kc) = o;
  }
}

// ---------------- layernorm: one wave per row, 4 rows/block ----------------
__global__ __launch_bounds__(256) void k_ln4(const float* __restrict__ x,
    const float* __restrict__ g, const float* __restrict__ b,
    unsigned short* __restrict__ out) {
  const int row = blockIdx.x * 4 + (threadIdx.x >> 6);
  const int l = threadIdx.x & 63;
  const float* xr = x + (long)row * 1024 + l * 16;
  float4 v[4];
#pragma unroll
  for (int e = 0; e < 4; ++e) v[e] = ((const float4*)xr)[e];
  float s = 0.0f;
#pragma unroll
  for (int e = 0; e < 4; ++e) s += v[e].x + v[e].y + v[e].z + v[e].w;
#pragma unroll
  for (int off = 32; off; off >>= 1) s += __shfl_xor(s, off);
  float mean = s * (1.0f / 1024.0f);
  float sq = 0.0f;
#pragma unroll
  for (int e = 0; e < 4; ++e) {
    float a0 = v[e].x - mean, a1 = v[e].y - mean, a2 = v[e].z - mean, a3 = v[e].w - mean;
    sq += a0 * a0 + a1 * a1 + a2 * a2 + a3 * a3;
  }
#pragma unroll
  for (int off = 32; off; off >>= 1) sq += __shfl_xor(sq, off);
  float inv = rsqrtf(sq * (1.0f / 1024.0f) + 1e-5f);
  const float* gr = g + l * 16;
  const float* br = b + l * 16;
  unsigned short* orow = out + (long)row * 1024 + l * 16;
#pragma unroll
  for (int e = 0; e < 4; ++e) {
    float4 gv = ((const float4*)gr)[e];
    float4 bv = ((const float4*)br)[e];
    ushort4 o;
    o.x = f2bf((v[e].x - mean) * inv * gv.x + bv.x);
    o.y = f2bf((v[e].y - mean) * inv * gv.y + bv.y);
    o.z = f2bf((v[e].z - mean) * inv * gv.z + bv.z);
    o.w = f2bf((v[e].w - mean) * inv * gv.w + bv.w);
    ((ushort4*)orow)[e] = o;
  }
}

// ---------------- MFMA flash local attention ----------------
__global__ __launch_bounds__(256, 2) void k_attn_mfma(
    const unsigned short* __restrict__ qkv, const float* __restrict__ table,
    unsigned short* __restrict__ o) {
  __shared__ unsigned short Ks[64 * 64];      // swizzled rows (key), 8 chunks of 8
  __shared__ unsigned short Vt[64 * 72];      // Vt[d][key], stride 72
  __shared__ unsigned short Ps[4][16 * 72];   // per-wave P, stride 72
  __shared__ float biasl[1024];
  const int qt = blockIdx.x, h = blockIdx.y, wi = blockIdx.z;
  const int iw0 = qt * 64;
  const int t = threadIdx.x;
  const int w = t >> 6, l = t & 63;
  const int lq = l & 15, lk = l >> 4;

  for (int i = t; i < 1024; i += 256) biasl[i] = table[i * 16 + h];

  const unsigned short* qp = qkv + (long)(wi * 512 + iw0 + w * 16 + lq) * 3072 + h * 64;
  bf16x8 qf0 = *(const bf16x8*)(qp + lk * 8);
  bf16x8 qf1 = *(const bf16x8*)(qp + 32 + lk * 8);

  f32x4 oacc[4] = {};
  float mrun[4] = {-3.0e38f, -3.0e38f, -3.0e38f, -3.0e38f};
  float srun[4] = {};

  const int kt0 = (wi == 0) ? 8 : qt;
  const int kt1 = qt + 8;
  for (int kt = kt0; kt <= kt1; ++kt) {
    const int ktbase = kt * 64;
    const long kgbase = (long)((wi - 1) * 512 + ktbase);
    __syncthreads();
    {
      const unsigned short* Kg = qkv + kgbase * 3072 + 1024 + h * 64;
#pragma unroll
      for (int s2 = 0; s2 < 2; ++s2) {
        int g = s2 * 4 + w;
        int row = g * 8 + (l >> 3);
        int gch = (l & 7) ^ (row & 7);
        gload_lds16(Kg + (long)row * 3072 + gch * 8, &Ks[g * 512]);
      }
    }
    {
      int kp = t & 31, dg = t >> 5;
      const unsigned short* Vg =
          qkv + (kgbase + 2 * kp) * 3072 + 2048 + h * 64 + dg * 8;
      bf16x8 a0 = *(const bf16x8*)Vg;
      bf16x8 a1 = *(const bf16x8*)(Vg + 3072);
#pragma unroll
      for (int e = 0; e < 8; ++e) {
        unsigned pack = ((unsigned)(unsigned short)a0[e]) |
                        (((unsigned)(unsigned short)a1[e]) << 16);
        *(unsigned*)&Vt[(dg * 8 + e) * 72 + 2 * kp] = pack;
      }
    }
    asm volatile("s_waitcnt vmcnt(0)" ::: "memory");
    __syncthreads();

    f32x4 sacc[4] = {};
#pragma unroll
    for (int ct = 0; ct < 4; ++ct) {
      int krow = ct * 16 + lq;
      bf16x8 kf0 = *(const bf16x8*)&Ks[krow * 64 + (((0 + lk) ^ (krow & 7)) * 8)];
      bf16x8 kf1 = *(const bf16x8*)&Ks[krow * 64 + (((4 + lk) ^ (krow & 7)) * 8)];
      sacc[ct] = __builtin_amdgcn_mfma_f32_16x16x32_bf16(qf0, kf0, sacc[ct], 0, 0, 0);
      sacc[ct] = __builtin_amdgcn_mfma_f32_16x16x32_bf16(qf1, kf1, sacc[ct], 0, 0, 0);
    }

#pragma unroll
    for (int r = 0; r < 4; ++r) {
      const int iw = iw0 + w * 16 + lk * 4 + r;
      float sc[4];
#pragma unroll
      for (int ct = 0; ct < 4; ++ct) {
        int jj = ktbase + ct * 16 + lq;
        int di = 512 + iw - jj;
        int dic = min(max(di, 0), 1023);
        bool allowed = (jj >= iw) && (jj <= iw + 512);
        float v = sacc[ct][r] * 0.125f + biasl[dic];
        sc[ct] = allowed ? v : -3.0e38f;
      }
      float mx = fmaxf(fmaxf(sc[0], sc[1]), fmaxf(sc[2], sc[3]));
      mx = fmaxf(mx, __shfl_xor(mx, 1));
      mx = fmaxf(mx, __shfl_xor(mx, 2));
      mx = fmaxf(mx, __shfl_xor(mx, 4));
      mx = fmaxf(mx, __shfl_xor(mx, 8));
      float mnew = fmaxf(mrun[r], mx);
      float f = __expf(mrun[r] - mnew);
      mrun[r] = mnew;
      float rs = 0.0f;
#pragma unroll
      for (int ct = 0; ct < 4; ++ct) {
        float pv = __expf(sc[ct] - mnew);
        rs += pv;
        Ps[w][(lk * 4 + r) * 72 + ct * 16 + lq] = f2bf(pv);
      }
      rs += __shfl_xor(rs, 1);
      rs += __shfl_xor(rs, 2);
      rs += __shfl_xor(rs, 4);
      rs += __shfl_xor(rs, 8);
      srun[r] = srun[r] * f + rs;
#pragma unroll
      for (int dt = 0; dt < 4; ++dt) oacc[dt][r] *= f;
    }
    asm volatile("s_waitcnt lgkmcnt(0)" ::: "memory");

#pragma unroll
    for (int ks = 0; ks < 2; ++ks) {
      bf16x4 pa0 = *(const bf16x4*)&Ps[w][lq * 72 + ks * 32 + lk * 8];
      bf16x4 pa1 = *(const bf16x4*)&Ps[w][lq * 72 + ks * 32 + lk * 8 + 4];
      bf16x8 pa = __builtin_shufflevector(pa0, pa1, 0, 1, 2, 3, 4, 5, 6, 7);
#pragma unroll
      for (int dt = 0; dt < 4; ++dt) {
        int drow = dt * 16 + lq;
        bf16x4 vb0 = *(const bf16x4*)&Vt[drow * 72 + ks * 32 + lk * 8];
        bf16x4 vb1 = *(const bf16x4*)&Vt[drow * 72 + ks * 32 + lk * 8 + 4];
        bf16x8 vb = __builtin_shufflevector(vb0, vb1, 0, 1, 2, 3, 4, 5, 6, 7);
        oacc[dt] = __builtin_amdgcn_mfma_f32_16x16x32_bf16(pa, vb, oacc[dt], 0, 0, 0);
      }
    }
  }

  unsigned short* ob =
      o + (long)(wi * 512 + iw0 + w * 16 + lk * 4) * 1024 + h * 64 + lq;
#pragma unroll
  for (int r = 0; r < 4; ++r) {
    float inv = 1.0f / srun[r];
#pragma unroll
    for (int dt = 0; dt < 4; ++dt)
      ob[(long)r * 1024 + dt * 16] = f2bf(oacc[dt][r] * inv);
  }
}

// ---------------- GEMM: C(M,N) = A(M,K) * B^T(N,K), bf16 MFMA ----------------
// 1D grid, bm-fast ordering + bijective XCD swizzle for B-panel L2 reuse.
// BM: 128 or 64 (M-tile). N-tile fixed 128.
// EPI: 0 = store bf16, 1 = fp32 +=, 2 = store fp32,
//      3 = fused GLU (interleaved a/gate cols) -> bf16 u at stride N/2
template <int EPI, int BM>
__global__ __launch_bounds__(256, 2) void k_gemm(const unsigned short* __restrict__ A,
    const unsigned short* __restrict__ BT, void* __restrict__ Cout,
    int N, int K, int nbm) {
  constexpr int MI = BM / 32;  // fragments per wave along M
  __shared__ unsigned short As[BM * 64];
  __shared__ unsigned short Bs[128 * 64];
  const int nwg = gridDim.x;
  const int orig = blockIdx.x;
  const int q8 = nwg >> 3, r8 = nwg & 7;
  const int xcd = orig & 7, i8 = orig >> 3;
  const int wgid = (xcd < r8 ? xcd * (q8 + 1) : r8 * (q8 + 1) + (xcd - r8) * q8) + i8;
  const int bm = wgid % nbm;  // bm-fast: consecutive blocks share the B panel
  const int bn = wgid / nbm;
  const int t = threadIdx.x;
  const int w = t >> 6, l = t & 63;
  const int wm = w >> 1, wn = w & 1;   // 2x2 waves
  const int lrow = l >> 3, lch = l & 7;
  const int lq = l & 15, lk = l >> 4;
  f32x4 acc[MI][4] = {};
  const long arow0 = (long)bm * BM, brow0 = (long)bn * 128;
  for (int kt = 0; kt < K; kt += 64) {
    __syncthreads();
#pragma unroll
    for (int s2 = 0; s2 < 4; ++s2) {
      int grp = s2 * 4 + w;
      int r = grp * 8 + lrow;
      int gch = lch ^ lrow;
      gload_lds16(BT + (brow0 + r) * K + kt + gch * 8, &Bs[grp * 512]);
      if (s2 < MI)
        gload_lds16(A + (arow0 + r) * K + kt + gch * 8, &As[grp * 512]);
    }
    asm volatile("s_waitcnt vmcnt(0)" ::: "memory");
    __syncthreads();
#pragma unroll
    for (int kk = 0; kk < 2; ++kk) {
      bf16x8 af[MI], bfr[4];
#pragma unroll
      for (int i = 0; i < MI; ++i) {
        int ra = wm * (BM / 2) + i * 16 + lq;
        af[i] = *(const bf16x8*)&As[ra * 64 + (((kk * 4 + lk) ^ (ra & 7)) * 8)];
      }
#pragma unroll
      for (int j = 0; j < 4; ++j) {
        int rb = wn * 64 + j * 16 + lq;
        bfr[j] = *(const bf16x8*)&Bs[rb * 64 + (((kk * 4 + lk) ^ (rb & 7)) * 8)];
      }
#pragma unroll
      for (int i = 0; i < MI; ++i)
#pragma unroll
        for (int j = 0; j < 4; ++j)
          acc[i][j] = __builtin_amdgcn_mfma_f32_16x16x32_bf16(af[i], bfr[j],
                                                              acc[i][j], 0, 0, 0);
    }
  }
  const int rbase = bm * BM + wm * (BM / 2) + lk * 4;
  const int cbase = bn * 128 + wn * 64 + lq;
#pragma unroll
  for (int i = 0; i < MI; ++i) {
#pragma unroll
    for (int j = 0; j < 4; ++j) {
#pragma unroll
      for (int r2 = 0; r2 < 4; ++r2) {
        long row = rbase + i * 16 + r2;
        long col = cbase + j * 16;
        float v = acc[i][j][r2];
        if (EPI == 0) {
          ((unsigned short*)Cout)[row * N + col] = f2bf(v);
        } else if (EPI == 1) {
          ((float*)Cout)[row * N + col] += v;
        } else if (EPI == 2) {
          ((float*)Cout)[row * N + col] = v;
        } else {
          // fused GLU: even col = a, odd col = gate (same feature f = col>>1)
          float gpart = __shfl_xor(v, 1);
          if ((lq & 1) == 0) {
            float uval =
                v * (0.5f * gpart * (1.0f + erff(gpart * 0.70710678118654752f)));
            ((unsigned short*)Cout)[row * (N >> 1) + (col >> 1)] = f2bf(uval);
          }
        }
      }
    }
  }
}

extern "C" void kernel_launch(void* const* d_in, const int* in_sizes, int n_in,
                              void* d_out, int out_size, void* d_ws, size_t ws_size,
                              hipStream_t stream) {
  (void)in_sizes; (void)n_in; (void)out_size; (void)ws_size;
  const int* tokens   = (const int*)d_in[0];
  const float* tok_emb = (const float*)d_in[1];
  const float* pos_emb = (const float*)d_in[2];
  const float* dpb_w1 = (const float*)d_in[3];
  const float* dpb_b1 = (const float*)d_in[4];
  const float* dpb_w2 = (const float*)d_in[5];
  const float* dpb_b2 = (const float*)d_in[6];
  const float* dpb_w3 = (const float*)d_in[7];
  const float* dpb_b3 = (const float*)d_in[8];
  const float* ln1_g  = (const float*)d_in[9];
  const float* ln1_b  = (const float*)d_in[10];
  const float* Wqkv   = (const float*)d_in[11];
  const float* Wo     = (const float*)d_in[12];
  const float* ln2_g  = (const float*)d_in[13];
  const float* ln2_b  = (const float*)d_in[14];
  const float* Wff1   = (const float*)d_in[15];
  const float* Wff2   = (const float*)d_in[16];
  const float* lnf_g  = (const float*)d_in[17];
  const float* lnf_b  = (const float*)d_in[18];
  const float* Wlog   = (const float*)d_in[19];
  float* out = (float*)d_out;

  char* p = (char*)d_ws;
  auto carve = [&](size_t bytes) {
    char* q = p;
    p += (bytes + 255) & ~(size_t)255;
    return (void*)q;
  };
  unsigned short* WqkvT = (unsigned short*)carve((size_t)4 * 3072 * 1024 * 2);
  unsigned short* WoT   = (unsigned short*)carve((size_t)4 * 1024 * 1024 * 2);
  unsigned short* Wff1T = (unsigned short*)carve((size_t)4 * 5504 * 1024 * 2);
  unsigned short* Wff2T = (unsigned short*)carve((size_t)4 * 1024 * 2752 * 2);
  unsigned short* WlogT = (unsigned short*)carve((size_t)32000 * 1024 * 2);
  float*          x     = (float*)carve((size_t)2048 * 1024 * 4);
  unsigned short* hbuf  = (unsigned short*)carve((size_t)2048 * 1024 * 2);
  unsigned short* qkv   = (unsigned short*)carve((size_t)2048 * 3072 * 2);
  unsigned short* ao    = (unsigned short*)carve((size_t)2048 * 1024 * 2);
  unsigned short* ubuf  = (unsigned short*)carve((size_t)2048 * 2752 * 2);
  float*          table = (float*)carve((size_t)1024 * 16 * 4);

  // prep: embed(2048) + dpb(1024) + wconv(20352) = 23424 blocks, one launch
  k_prep<<<23424, 256, 0, stream>>>(
      tokens, tok_emb, pos_emb, x, dpb_w1, dpb_b1, dpb_w2, dpb_b2, dpb_w3,
      dpb_b3, table, Wqkv, WqkvT, Wo, WoT, Wff1, Wff1T, Wff2, Wff2T, Wlog, WlogT);

  for (int l = 0; l < 4; ++l) {
    k_ln4<<<512, 256, 0, stream>>>(x, ln1_g + l * 1024, ln1_b + l * 1024, hbuf);
    k_gemm<0, 128><<<dim3(16 * (3072 / 128)), 256, 0, stream>>>(
        hbuf, WqkvT + (long)l * 3072 * 1024, qkv, 3072, 1024, 16);
    k_attn_mfma<<<dim3(8, 16, 4), 256, 0, stream>>>(qkv, table, ao);
    k_gemm<1, 64><<<dim3(32 * (1024 / 128)), 256, 0, stream>>>(
        ao, WoT + (long)l * 1024 * 1024, x, 1024, 1024, 32);
    k_ln4<<<512, 256, 0, stream>>>(x, ln2_g + l * 1024, ln2_b + l * 1024, hbuf);
    k_gemm<3, 128><<<dim3(16 * (5504 / 128)), 256, 0, stream>>>(
        hbuf, Wff1T + (long)l * 5504 * 1024, ubuf, 5504, 1024, 16);
    k_gemm<1, 64><<<dim3(32 * (1024 / 128)), 256, 0, stream>>>(
        ubuf, Wff2T + (long)l * 1024 * 2752, x, 1024, 2752, 32);
  }
  k_ln4<<<512, 256, 0, stream>>>(x, lnf_g, lnf_b, hbuf);
  k_gemm<2, 128><<<dim3(16 * (32000 / 128)), 256, 0, stream>>>(
      hbuf, WlogT, out, 32000, 1024, 16);
}